// Round 18
// baseline (819.087 us; speedup 1.0000x reference)
//
#include <hip/hip_runtime.h>
#include <hip/hip_bf16.h>
#include <math.h>

using bf16 = __hip_bfloat16;

namespace {

constexpr int cH = 2048;
constexpr int cNH = 16;
constexpr int cHD = 128;
constexpr int cNFW = 4;
constexpr int cFD = 512;
constexpr int cS = 2048;
constexpr float cRSQRT_HD = 0.08838834764831845f;  // 1/sqrt(128)
constexpr long ZL_ = 262144;   // 512*512
constexpr long ZG_ = 1048576;  // 2048*512

typedef __attribute__((ext_vector_type(8))) short short8;
typedef __attribute__((ext_vector_type(4))) float f32x4;

__device__ __forceinline__ float sigmoidf_(float x) { return 1.0f / (1.0f + __expf(-x)); }
__device__ __forceinline__ float b2f(bf16 v) { return __bfloat162float(v); }
__device__ __forceinline__ bf16 f2b(float v) { return __float2bfloat16(v); }
__device__ __forceinline__ unsigned short f2bu(float f) {
  return __builtin_bit_cast(unsigned short, __float2bfloat16(f));
}
__device__ __forceinline__ float bu2f(unsigned u) { return __uint_as_float(u << 16); }

#if defined(__has_builtin)
#if __has_builtin(__builtin_amdgcn_global_load_lds)
#define HAVE_GLOAD 1
#endif
#endif

__device__ __forceinline__ void gload16(const bf16* g, short* ldsbase) {
#ifdef HAVE_GLOAD
  __builtin_amdgcn_global_load_lds((const __attribute__((address_space(1))) void*)g,
                                   (__attribute__((address_space(3))) void*)ldsbase, 16, 0, 0);
#else
  const int l = threadIdx.x & 63;
  *(uint4*)(ldsbase + l * 8) = *(const uint4*)g;
#endif
}

__device__ __forceinline__ void stage16(const bf16* src, short* dst) {
  *(uint4*)dst = *(const uint4*)src;
  *(uint4*)(dst + 8) = *(const uint4*)(src + 8);
}

__device__ __forceinline__ void store1(float* p, float v) { *p = v; }
__device__ __forceinline__ void store1(bf16* p, float v) { *p = f2b(v); }

// ---------------------------------------------------------------------------
// MFMA NT GEMM core: 128x128 tile, 4 waves (2x2 of 64x64), BK=32, linear LDS.
// (used by fuse1/updna TTT kernels)
// ---------------------------------------------------------------------------
__device__ __forceinline__ void mm_core32(const bf16* __restrict__ Ab, int lda,
                                          const bf16* __restrict__ Bb, int ldb, int K,
                                          short* As, short* Bs, f32x4 acc[4][4]) {
  const int t = threadIdx.x, lane = t & 63, g = lane >> 4, c16 = lane & 15;
  const int wv = t >> 6, wm = (wv >> 1) * 64, wn = (wv & 1) * 64;
  for (int k0 = 0; k0 < K; k0 += 32) {
    __syncthreads();
    {
      const int ch = wv * 2;
      const bf16* ga = Ab + (size_t)(ch * 16 + (lane >> 2)) * lda + k0 + (lane & 3) * 8;
      gload16(ga, &As[ch * 512]);
      gload16(ga + (size_t)16 * lda, &As[ch * 512 + 512]);
      const bf16* gb = Bb + (size_t)(ch * 16 + (lane >> 2)) * ldb + k0 + (lane & 3) * 8;
      gload16(gb, &Bs[ch * 512]);
      gload16(gb + (size_t)16 * ldb, &Bs[ch * 512 + 512]);
    }
    __syncthreads();
    short8 af[4], bfr[4];
#pragma unroll
    for (int mi = 0; mi < 4; ++mi) af[mi] = *(const short8*)&As[(wm + mi * 16 + c16) * 32 + g * 8];
#pragma unroll
    for (int ni = 0; ni < 4; ++ni) bfr[ni] = *(const short8*)&Bs[(wn + ni * 16 + c16) * 32 + g * 8];
#pragma unroll
    for (int mi = 0; mi < 4; ++mi)
#pragma unroll
      for (int ni = 0; ni < 4; ++ni)
        acc[mi][ni] = __builtin_amdgcn_mfma_f32_16x16x32_bf16(af[mi], bfr[ni], acc[mi][ni], 0, 0, 0);
  }
}

template <bool ACC, bool MIR, typename TC>
__device__ __forceinline__ void mm_store(TC* Cb, bf16* Mb, int ldc, int rb, int cb, f32x4 acc[4][4]) {
  const int t = threadIdx.x, lane = t & 63, g = lane >> 4, c16 = lane & 15;
  const int wv = t >> 6, wm = (wv >> 1) * 64, wn = (wv & 1) * 64;
  const int rbase = rb + wm, cbase = cb + wn;
#pragma unroll
  for (int mi = 0; mi < 4; ++mi)
#pragma unroll
    for (int ni = 0; ni < 4; ++ni) {
      const int col = cbase + ni * 16 + c16;
#pragma unroll
      for (int r = 0; r < 4; ++r) {
        const int row = rbase + mi * 16 + g * 4 + r;
        TC* cp = Cb + (size_t)row * ldc + col;
        if constexpr (ACC) {
          float nv = *cp + acc[mi][ni][r];
          *cp = nv;
          if constexpr (MIR) Mb[(size_t)row * ldc + col] = f2b(nv);
        } else {
          store1(cp, acc[mi][ni][r]);
        }
      }
    }
}

// ---------------------------------------------------------------------------
// Pipelined GEMM: 256(M)x128(N) tile, 8 waves (4Mx2N), BK=64.
// A-operand: direct global->VGPR in MFMA fragment layout, double-buffered.
// B-operand: LDS, 3-deep rotation, chunk-XOR swizzle, counted vmcnt(4),
// ONE s_barrier per K-tile.  K%64==0 and K/64 even; M%256==0, N%128==0.
// ---------------------------------------------------------------------------
template <typename TC>
__global__ __launch_bounds__(512, 1) void k_mm8(const bf16* __restrict__ A, int lda,
                                                const bf16* __restrict__ B, int ldb,
                                                TC* __restrict__ C, int ldc, int K) {
  __shared__ short LB[3][128 * 64];  // 48 KB
  const int t = threadIdx.x, lane = t & 63, wv = t >> 6;
  const int g = lane >> 4, c16 = lane & 15;
  const int wm = (wv >> 1) * 64, wn = (wv & 1) * 64;
  const bf16* Ab = A + (size_t)blockIdx.y * 256 * lda;
  const bf16* Bb = B + (size_t)blockIdx.x * 128 * ldb;
  const int NKT = K >> 6;
  const int srow = wv * 16 + (lane >> 3);
  // source-permuted column: LDS slot (r, c) receives global chunk c ^ (r&7)
  const int scol = ((lane & 7) ^ ((lane >> 3) & 7)) * 8;

  auto stB = [&](int buf, int kt) {
    const int ktc = (kt < NKT) ? kt : 0;
    const bf16* src = Bb + (size_t)srow * ldb + ktc * 64 + scol;
    short* dst = &LB[buf][(wv * 16) * 64];
    gload16(src, dst);
    gload16(src + (size_t)8 * ldb, dst + 512);
  };
  // A fragment loader: 8 short8 for tile kt, direct from global (MFMA layout)
  auto loadA = [&](short8 dst[4][2], int kt) {
    const int ktc = (kt < NKT) ? kt : 0;
#pragma unroll
    for (int f = 0; f < 4; ++f)
#pragma unroll
      for (int kk = 0; kk < 2; ++kk)
        dst[f][kk] = *(const short8*)(Ab + (size_t)(wm + f * 16 + c16) * lda +
                                      ktc * 64 + kk * 32 + g * 8);
  };

  f32x4 acc[4][4];
  const f32x4 zero4 = {0.f, 0.f, 0.f, 0.f};
#pragma unroll
  for (int i = 0; i < 4; ++i)
#pragma unroll
    for (int j = 0; j < 4; ++j) acc[i][j] = zero4;

  short8 afE[4][2], afO[4][2];

  // prologue: B tiles 0,1 staged; A tile 0 in regs
  stB(0, 0);
  stB(1, 1);
  loadA(afE, 0);
  asm volatile("s_waitcnt vmcnt(0)" ::: "memory");
  __builtin_amdgcn_s_barrier();

  int rb = 0;           // read buffer = kt % 3
  for (int it = 0; it < NKT; it += 2) {
    // ---- even phase: kt = it, cur = afE, nxt = afO ----
    {
      const int kt = it;
      const int sb = (rb >= 1) ? rb - 1 : 2;  // (kt+2) % 3
      loadA(afO, kt + 1);
      stB(sb, kt + 2);
      short8 bfr[4][2];
#pragma unroll
      for (int ni = 0; ni < 4; ++ni)
#pragma unroll
        for (int kk = 0; kk < 2; ++kk) {
          const int rr = wn + ni * 16 + c16;
          bfr[ni][kk] = *(const short8*)&LB[rb][rr * 64 + ((kk * 4 + g) ^ (rr & 7)) * 8];
        }
      __builtin_amdgcn_s_setprio(1);
#pragma unroll
      for (int f = 0; f < 4; ++f)
#pragma unroll
        for (int ni = 0; ni < 4; ++ni)
#pragma unroll
          for (int kk = 0; kk < 2; ++kk)
            acc[f][ni] = __builtin_amdgcn_mfma_f32_16x16x32_bf16(
                afE[f][kk], bfr[ni][kk], acc[f][ni], 0, 0, 0);
      __builtin_amdgcn_s_setprio(0);
      asm volatile("s_waitcnt vmcnt(4)" ::: "memory");
      __builtin_amdgcn_s_barrier();
      rb = (rb + 1 < 3) ? rb + 1 : 0;
    }
    // ---- odd phase: kt = it+1, cur = afO, nxt = afE ----
    {
      const int kt = it + 1;
      const int sb = (rb >= 1) ? rb - 1 : 2;
      loadA(afE, kt + 1);
      stB(sb, kt + 2);
      short8 bfr[4][2];
#pragma unroll
      for (int ni = 0; ni < 4; ++ni)
#pragma unroll
        for (int kk = 0; kk < 2; ++kk) {
          const int rr = wn + ni * 16 + c16;
          bfr[ni][kk] = *(const short8*)&LB[rb][rr * 64 + ((kk * 4 + g) ^ (rr & 7)) * 8];
        }
      __builtin_amdgcn_s_setprio(1);
#pragma unroll
      for (int f = 0; f < 4; ++f)
#pragma unroll
        for (int ni = 0; ni < 4; ++ni)
#pragma unroll
          for (int kk = 0; kk < 2; ++kk)
            acc[f][ni] = __builtin_amdgcn_mfma_f32_16x16x32_bf16(
                afO[f][kk], bfr[ni][kk], acc[f][ni], 0, 0, 0);
      __builtin_amdgcn_s_setprio(0);
      asm volatile("s_waitcnt vmcnt(4)" ::: "memory");
      __builtin_amdgcn_s_barrier();
      rb = (rb + 1 < 3) ? rb + 1 : 0;
    }
  }

  const int rbase = blockIdx.y * 256 + wm, cbase = blockIdx.x * 128 + wn;
#pragma unroll
  for (int fr = 0; fr < 4; ++fr)
#pragma unroll
    for (int ni = 0; ni < 4; ++ni) {
      const int col = cbase + ni * 16 + c16;
#pragma unroll
      for (int r = 0; r < 4; ++r)
        store1(C + (size_t)(rbase + fr * 16 + g * 4 + r) * ldc + col, acc[fr][ni][r]);
    }
}

// ---------------------------------------------------------------------------
// Fused stage1 + gates + (trK,trV transposes) + (prev-chunk norm-add).
// ---------------------------------------------------------------------------
__global__ __launch_bounds__(256) void k_fuse1(const bf16* __restrict__ fq, const bf16* __restrict__ fk,
                                               const bf16* __restrict__ fv,
                                               const bf16* __restrict__ w0b, const bf16* __restrict__ w1t,
                                               const bf16* __restrict__ w2b,
                                               bf16* __restrict__ hq, bf16* __restrict__ trH,
                                               bf16* __restrict__ trD1, bf16* __restrict__ trD2,
                                               bf16* __restrict__ trK, bf16* __restrict__ trV,
                                               const float* __restrict__ lr0, const float* __restrict__ lr1,
                                               const float* __restrict__ lr2,
                                               const bf16* __restrict__ occ,
                                               const float* __restrict__ tw, bf16* __restrict__ y,
                                               int chunk) {
  __shared__ short S[12288];
  __shared__ float red[4];
  const int id = blockIdx.x, t = threadIdx.x;
  const size_t choff = (size_t)chunk * 262144;

  if (id < 512) {
    const int bh = id >> 6, tile = id & 63, by = tile >> 3, bx = tile & 7;
    const int lane = t & 63, g = lane >> 4, c16 = lane & 15, wv = t >> 6;
    const int wm = (wv >> 1) * 32, wn = (wv & 1) * 32;
    const bf16* Aq = fq + (size_t)bh * ZG_ + choff + (size_t)(by * 64) * cFD;
    const bf16* Ak = fk + (size_t)bh * ZG_ + choff + (size_t)(by * 64) * cFD;
    const bf16* Av = fv + (size_t)bh * ZG_ + choff + (size_t)(by * 64) * cFD;
    const bf16* B0 = w0b + (size_t)bh * ZL_ + (size_t)(bx * 64) * cFD;
    const bf16* B2 = w2b + (size_t)bh * ZL_ + (size_t)(bx * 64) * cFD;
    const bf16* B1 = w1t + (size_t)bh * ZL_ + (size_t)(bx * 64) * cFD;  // [e][d]

    f32x4 acc[5][2][2];
    const f32x4 zero4 = {0.f, 0.f, 0.f, 0.f};
#pragma unroll
    for (int v = 0; v < 5; ++v)
#pragma unroll
      for (int i = 0; i < 2; ++i)
#pragma unroll
        for (int j = 0; j < 2; ++j) acc[v][i][j] = zero4;

    const int srow = wv * 16 + (lane >> 2), scol = (lane & 3) * 8;
    for (int k0 = 0; k0 < 512; k0 += 32) {
      __syncthreads();
      gload16(Aq + (size_t)srow * cFD + k0 + scol, &S[0 + wv * 512]);
      gload16(Ak + (size_t)srow * cFD + k0 + scol, &S[2048 + wv * 512]);
      gload16(Av + (size_t)srow * cFD + k0 + scol, &S[4096 + wv * 512]);
      gload16(B0 + (size_t)srow * cFD + k0 + scol, &S[6144 + wv * 512]);
      gload16(B2 + (size_t)srow * cFD + k0 + scol, &S[8192 + wv * 512]);
      gload16(B1 + (size_t)srow * cFD + k0 + scol, &S[10240 + wv * 512]);
      __syncthreads();
      short8 aq[2], ak[2], av[2], b0[2], b2[2], b1[2];
#pragma unroll
      for (int mi = 0; mi < 2; ++mi) {
        const int ro = (wm + mi * 16 + c16) * 32 + g * 8;
        aq[mi] = *(const short8*)&S[0 + ro];
        ak[mi] = *(const short8*)&S[2048 + ro];
        av[mi] = *(const short8*)&S[4096 + ro];
      }
#pragma unroll
      for (int ni = 0; ni < 2; ++ni) {
        const int ro = (wn + ni * 16 + c16) * 32 + g * 8;
        b0[ni] = *(const short8*)&S[6144 + ro];
        b2[ni] = *(const short8*)&S[8192 + ro];
        b1[ni] = *(const short8*)&S[10240 + ro];
      }
#pragma unroll
      for (int mi = 0; mi < 2; ++mi)
#pragma unroll
        for (int ni = 0; ni < 2; ++ni) {
          acc[0][mi][ni] = __builtin_amdgcn_mfma_f32_16x16x32_bf16(aq[mi], b0[ni], acc[0][mi][ni], 0, 0, 0);
          acc[1][mi][ni] = __builtin_amdgcn_mfma_f32_16x16x32_bf16(aq[mi], b2[ni], acc[1][mi][ni], 0, 0, 0);
          acc[2][mi][ni] = __builtin_amdgcn_mfma_f32_16x16x32_bf16(ak[mi], b0[ni], acc[2][mi][ni], 0, 0, 0);
          acc[3][mi][ni] = __builtin_amdgcn_mfma_f32_16x16x32_bf16(ak[mi], b2[ni], acc[3][mi][ni], 0, 0, 0);
          acc[4][mi][ni] = __builtin_amdgcn_mfma_f32_16x16x32_bf16(av[mi], b1[ni], acc[4][mi][ni], 0, 0, 0);
        }
    }

    float l0v[2][4], l2v[2][4];
#pragma unroll
    for (int mi = 0; mi < 2; ++mi)
#pragma unroll
      for (int r = 0; r < 4; ++r) {
        const int row = by * 64 + wm + mi * 16 + g * 4 + r;
        l0v[mi][r] = lr0[bh * 2048 + chunk * 512 + row];
        l2v[mi][r] = lr2[bh * 2048 + chunk * 512 + row];
      }
#pragma unroll
    for (int mi = 0; mi < 2; ++mi)
#pragma unroll
      for (int ni = 0; ni < 2; ++ni)
#pragma unroll
        for (int r = 0; r < 4; ++r) {
          float hq1 = acc[0][mi][ni][r], hq2 = acc[1][mi][ni][r];
          float g1 = acc[2][mi][ni][r], g2 = acc[3][mi][ni][r], dh = acc[4][mi][ni][r];
          acc[0][mi][ni][r] = hq1 * sigmoidf_(hq1) * hq2;
          float sg = sigmoidf_(g1);
          float gate = g1 * sg;
          acc[1][mi][ni][r] = gate * g2;
          acc[2][mi][ni][r] = l0v[mi][r] * dh * g2 * (sg * (1.0f + g1 * (1.0f - sg)));
          acc[3][mi][ni][r] = l2v[mi][r] * dh * gate;
        }

    short* Ts = S;
    bf16* dst0 = hq + (size_t)bh * ZL_;
    bf16* dstT[3] = {trH + (size_t)bh * ZL_, trD1 + (size_t)bh * ZL_, trD2 + (size_t)bh * ZL_};
#pragma unroll
    for (int rd = 0; rd < 4; ++rd) {
      __syncthreads();
#pragma unroll
      for (int mi = 0; mi < 2; ++mi)
#pragma unroll
        for (int ni = 0; ni < 2; ++ni)
#pragma unroll
          for (int r = 0; r < 4; ++r) {
            const int row = wm + mi * 16 + g * 4 + r, col = wn + ni * 16 + c16;
            if (rd == 0) Ts[row * 66 + col] = (short)f2bu(acc[0][mi][ni][r]);
            else Ts[col * 66 + row] = (short)f2bu(acc[rd][mi][ni][r]);
          }
      __syncthreads();
      const int rr = t >> 2, cs = (t & 3) * 16;
      unsigned short u[16] __attribute__((aligned(16)));
#pragma unroll
      for (int i = 0; i < 16; ++i) u[i] = (unsigned short)Ts[rr * 66 + cs + i];
      bf16* dp = (rd == 0) ? (dst0 + (size_t)(by * 64 + rr) * cFD + bx * 64 + cs)
                           : (dstT[rd - 1] + (size_t)(bx * 64 + rr) * cFD + by * 64 + cs);
      *(uint4*)dp = *(uint4*)u;
      *(uint4*)(dp + 8) = *(uint4*)(u + 8);
    }
  } else if (id < 1536) {
    short* Ts = S;  // 64*72
    const int id2 = id - 512;
    const int var = id2 >> 9, bh = (id2 >> 6) & 7, by = (id2 >> 3) & 7, bx = id2 & 7;
    const bf16* src = ((var == 0) ? fk : fv) + choff + (size_t)bh * ZG_;
    bf16* dst = ((var == 0) ? trK : trV) + (size_t)bh * ZL_;
    {
      const int rr = t >> 2, cseg = (t & 3) * 16;
      if (var == 0) {
        stage16(src + (size_t)(by * 64 + rr) * cFD + bx * 64 + cseg, &Ts[rr * 72 + cseg]);
      } else {
        const float s = lr1[bh * 2048 + chunk * 512 + by * 64 + rr];
        const bf16* p = src + (size_t)(by * 64 + rr) * cFD + bx * 64 + cseg;
        unsigned short u[16] __attribute__((aligned(16)));
#pragma unroll
        for (int i = 0; i < 16; ++i) u[i] = f2bu(b2f(p[i]) * s);
        *(uint4*)&Ts[rr * 72 + cseg] = *(uint4*)u;
        *(uint4*)&Ts[rr * 72 + cseg + 8] = *(uint4*)(u + 8);
      }
    }
    __syncthreads();
    {
      const int oc_ = t >> 2, rseg = (t & 3) * 16;
      unsigned short u[16] __attribute__((aligned(16)));
#pragma unroll
      for (int i = 0; i < 16; ++i) u[i] = (unsigned short)Ts[(rseg + i) * 72 + oc_];
      bf16* dp = dst + (size_t)(bx * 64 + oc_) * cFD + by * 64 + rseg;
      *(uint4*)dp = *(uint4*)u;
      *(uint4*)(dp + 8) = *(uint4*)(u + 8);
    }
  } else {
    const int rrow = id - 1536;
    const int bh = rrow >> 9, rr = rrow & 511;
    const bf16* src = occ + ((size_t)bh * 512 + rr) * 512;
    float v0 = b2f(src[t]), v1 = b2f(src[t + 256]);
    float ss = v0 * v0 + v1 * v1;
    for (int d = 32; d; d >>= 1) ss += __shfl_down(ss, d);
    if ((t & 63) == 0) red[t >> 6] = ss;
    __syncthreads();
    const float rstd = rsqrtf((red[0] + red[1] + red[2] + red[3]) / cFD + 1e-6f);
    const int si = (chunk - 1) * 512 + rr;
    bf16* dst = y + ((size_t)((bh >> 2) * cS) + si) * cH + (bh & 3) * cFD;
    dst[t] = f2b(b2f(dst[t]) + v0 * rstd * tw[t]);
    dst[t + 256] = f2b(b2f(dst[t + 256]) + v1 * rstd * tw[t + 256]);
  }
}

// ---------------------------------------------------------------------------
// updna: ids 0..383 weight-update GEMMs (var0 also writes w1t transposed);
//        ids 384..511 oc = hq @ w1_cur^T (128^2 tiles).
// ---------------------------------------------------------------------------
__global__ __launch_bounds__(256) void k_updna(const bf16* __restrict__ trV, const bf16* __restrict__ trH,
                                               const bf16* __restrict__ trD1, const bf16* __restrict__ trD2,
                                               const bf16* __restrict__ trK,
                                               const bf16* __restrict__ hq, const bf16* __restrict__ w1bc,
                                               float* w0s, float* w1s, float* w2s,
                                               bf16* w0b, bf16* w1bn, bf16* w2b, bf16* w1t,
                                               bf16* __restrict__ occ) {
  __shared__ short Sh[8704];
  const int id = blockIdx.x, t = threadIdx.x;
  const int lane = t & 63, g = lane >> 4, c16 = lane & 15, wv = t >> 6;
  if (id < 384) {
    short* As = Sh;
    short* Bs = Sh + 4096;
    const int z = id >> 4, tile = id & 15, by = tile >> 2, bx = tile & 3;
    const int var = z >> 3, bh = z & 7;
    const bf16 *Aa, *Bb;
    if (var == 0) {
      Aa = trV + (size_t)bh * ZL_ + (size_t)by * 128 * cFD;
      Bb = trH + (size_t)bh * ZL_ + (size_t)bx * 128 * cFD;
    } else if (var == 1) {
      Aa = trD1 + (size_t)bh * ZL_ + (size_t)by * 128 * cFD;
      Bb = trK + (size_t)bh * ZL_ + (size_t)bx * 128 * cFD;
    } else {
      Aa = trD2 + (size_t)bh * ZL_ + (size_t)by * 128 * cFD;
      Bb = trK + (size_t)bh * ZL_ + (size_t)bx * 128 * cFD;
    }
    f32x4 acc[4][4];
    const f32x4 zero4 = {0.f, 0.f, 0.f, 0.f};
#pragma unroll
    for (int i = 0; i < 4; ++i)
#pragma unroll
      for (int j = 0; j < 4; ++j) acc[i][j] = zero4;
    mm_core32(Aa, cFD, Bb, cFD, cFD, As, Bs, acc);
    if (var == 1) {
      mm_store<true, true>(w0s + (size_t)bh * ZL_, w0b + (size_t)bh * ZL_, cFD, by * 128, bx * 128, acc);
    } else if (var == 2) {
      mm_store<true, true>(w2s + (size_t)bh * ZL_, w2b + (size_t)bh * ZL_, cFD, by * 128, bx * 128, acc);
    } else {
      float* W = w1s + (size_t)bh * ZL_;
      bf16* M = w1bn + (size_t)bh * ZL_;
      const int wm = (wv >> 1) * 64, wn = (wv & 1) * 64;
#pragma unroll
      for (int mi = 0; mi < 4; ++mi)
#pragma unroll
        for (int ni = 0; ni < 4; ++ni) {
          const int col = bx * 128 + wn + ni * 16 + c16;
#pragma unroll
          for (int r = 0; r < 4; ++r) {
            const int row = by * 128 + wm + mi * 16 + g * 4 + r;
            float nv = W[(size_t)row * cFD + col] + acc[mi][ni][r];
            W[(size_t)row * cFD + col] = nv;
            M[(size_t)row * cFD + col] = f2b(nv);
            acc[mi][ni][r] = nv;
          }
        }
      bf16* T = w1t + (size_t)bh * ZL_;
      short* Ts = Sh;  // 64 cc x 136
#pragma unroll
      for (int rd = 0; rd < 2; ++rd) {
        __syncthreads();
        if (wn == rd * 64) {
#pragma unroll
          for (int mi = 0; mi < 4; ++mi)
#pragma unroll
            for (int ni = 0; ni < 4; ++ni) {
              const int cc = ni * 16 + c16;
              unsigned short u[4] __attribute__((aligned(8)));
#pragma unroll
              for (int r = 0; r < 4; ++r) u[r] = f2bu(acc[mi][ni][r]);
              *(uint2*)&Ts[cc * 136 + wm + mi * 16 + g * 4] = *(uint2*)u;
            }
        }
        __syncthreads();
        const int cc = t >> 2, seg = (t & 3) * 32;
        unsigned short u[32] __attribute__((aligned(16)));
#pragma unroll
        for (int i = 0; i < 32; ++i) u[i] = (unsigned short)Ts[cc * 136 + seg + i];
        bf16* dp = T + (size_t)(bx * 128 + rd * 64 + cc) * cFD + by * 128 + seg;
        *(uint4*)dp = *(uint4*)u;
        *(uint4*)(dp + 8) = *(uint4*)(u + 8);
        *(uint4*)(dp + 16) = *(uint4*)(u + 16);
        *(uint4*)(dp + 24) = *(uint4*)(u + 24);
      }
    }
  } else {
    short* As = Sh;
    short* Bs = Sh + 4096;
    const int id2 = id - 384;
    const int bh = id2 >> 4, tile = id2 & 15, by = tile >> 2, bx = tile & 3;
    const bf16* Aa = hq + (size_t)bh * ZL_ + (size_t)by * 128 * cFD;
    const bf16* Bb = w1bc + (size_t)bh * ZL_ + (size_t)bx * 128 * cFD;
    f32x4 acc[4][4];
    const f32x4 zero4 = {0.f, 0.f, 0.f, 0.f};
#pragma unroll
    for (int i = 0; i < 4; ++i)
#pragma unroll
      for (int j = 0; j < 4; ++j) acc[i][j] = zero4;
    mm_core32(Aa, cFD, Bb, cFD, cFD, As, Bs, acc);
    mm_store<false, false>(occ + (size_t)bh * ZL_, (bf16*)nullptr, cFD, by * 128, bx * 128, acc);
  }
}

// tail: ids 0..4095 final norm-add; 4096..6143 cvt o_proj_w -> opwb
__global__ __launch_bounds__(256) void k_normcvt(const bf16* __restrict__ occ,
                                                 const float* __restrict__ tw, bf16* __restrict__ y,
                                                 const float* __restrict__ opw, bf16* __restrict__ opwb,
                                                 int chunk) {
  __shared__ float red[4];
  const int id = blockIdx.x, t = threadIdx.x;
  if (id < 4096) {
    const int bh = id >> 9, rr = id & 511;
    const bf16* src = occ + ((size_t)bh * 512 + rr) * 512;
    float v0 = b2f(src[t]), v1 = b2f(src[t + 256]);
    float ss = v0 * v0 + v1 * v1;
    for (int d = 32; d; d >>= 1) ss += __shfl_down(ss, d);
    if ((t & 63) == 0) red[t >> 6] = ss;
    __syncthreads();
    const float rstd = rsqrtf((red[0] + red[1] + red[2] + red[3]) / cFD + 1e-6f);
    const int si = chunk * 512 + rr;
    bf16* dst = y + ((size_t)((bh >> 2) * cS) + si) * cH + (bh & 3) * cFD;
    dst[t] = f2b(b2f(dst[t]) + v0 * rstd * tw[t]);
    dst[t + 256] = f2b(b2f(dst[t + 256]) + v1 * rstd * tw[t + 256]);
  } else {
    const size_t i = ((size_t)(id - 4096) * 256 + t) * 8;
    float4 a = *(const float4*)(opw + i), b = *(const float4*)(opw + i + 4);
    unsigned short u[8] __attribute__((aligned(16)));
    u[0] = f2bu(a.x); u[1] = f2bu(a.y); u[2] = f2bu(a.z); u[3] = f2bu(a.w);
    u[4] = f2bu(b.x); u[5] = f2bu(b.y); u[6] = f2bu(b.z); u[7] = f2bu(b.w);
    *(uint4*)(opwb + i) = *(uint4*)u;
  }
}

// --- merged prep: cvt x, cvt qkv_w, winit (f4), rope table, lr projections --
__global__ __launch_bounds__(256) void k_prep(const float* __restrict__ x, const float* __restrict__ qkv_w,
                                              const float* __restrict__ w0, const float* __restrict__ w1,
                                              const float* __restrict__ w2,
                                              const float* __restrict__ lr_w, const float* __restrict__ lr_b,
                                              bf16* __restrict__ xb, bf16* __restrict__ qkvwb,
                                              float* __restrict__ w0s, float* __restrict__ w1s,
                                              float* __restrict__ w2s,
                                              float* __restrict__ ct, float* __restrict__ stb,
                                              float* lr0, float* lr1, float* lr2, float base) {
  __shared__ float xbuf[cH];
  const int id = blockIdx.x, t = threadIdx.x;
  if (id < 4096) {
    const size_t i = ((size_t)id * 256 + t) * 8;
    float4 a = *(const float4*)(x + i), b = *(const float4*)(x + i + 4);
    unsigned short u[8] __attribute__((aligned(16)));
    u[0] = f2bu(a.x); u[1] = f2bu(a.y); u[2] = f2bu(a.z); u[3] = f2bu(a.w);
    u[4] = f2bu(b.x); u[5] = f2bu(b.y); u[6] = f2bu(b.z); u[7] = f2bu(b.w);
    *(uint4*)(xb + i) = *(uint4*)u;
  } else if (id < 10240) {
    const size_t i = ((size_t)(id - 4096) * 256 + t) * 8;
    float4 a = *(const float4*)(qkv_w + i), b = *(const float4*)(qkv_w + i + 4);
    unsigned short u[8] __attribute__((aligned(16)));
    u[0] = f2bu(a.x); u[1] = f2bu(a.y); u[2] = f2bu(a.z); u[3] = f2bu(a.w);
    u[4] = f2bu(b.x); u[5] = f2bu(b.y); u[6] = f2bu(b.z); u[7] = f2bu(b.w);
    *(uint4*)(qkvwb + i) = *(uint4*)u;
  } else if (id < 16384) {
    const int sub = id - 10240;
    const int w = sub >> 11, blk = sub & 2047;
    const size_t i = ((size_t)blk * 256 + t) * 4;
    const int f = (int)((i >> 18) & 3);
    const size_t off = i & 262143;
    const float* src = (w == 0) ? w0 : (w == 1) ? w1 : w2;
    float* dst = (w == 0) ? w0s : (w == 1) ? w1s : w2s;
    *(float4*)(dst + i) = *(const float4*)(src + (size_t)f * 262144 + off);
  } else if (id < 16896) {
    const int gid = (id - 16384) * 256 + t;
    const int si = gid >> 6, jj = gid & 63;
    float inv = powf(500000.0f, -(float)jj / 64.0f);
    float ang = (float)si * inv;
    ct[(size_t)si * 64 + jj] = cosf(ang);
    stb[(size_t)si * 64 + jj] = sinf(ang);
  } else {
    const int token = id - 16896, b_ = token >> 11, si = token & 2047;
    const int wv = t >> 6, lane = t & 63;
    const float* xr = x + (size_t)token * cH;
    for (int i = t; i < cH; i += 256) xbuf[i] = xr[i];
    __syncthreads();
#pragma unroll
    for (int jj = 0; jj < 3; ++jj) {
      const int j = wv * 3 + jj;
      const float* wr = lr_w + (size_t)j * cH;
      float s = 0.f;
      for (int k = lane; k < cH; k += 64) s += xbuf[k] * wr[k];
      for (int d = 32; d; d >>= 1) s += __shfl_down(s, d);
      if (lane == 0) {
        float v = s + lr_b[j] + base;
        float sp = (v > 15.f) ? v : log1pf(expf(v));
        const int tt = j >> 2, f = j & 3;
        float* dst = (tt == 0 ? lr0 : tt == 1 ? lr1 : lr2);
        dst[(size_t)(b_ * cNFW + f) * cS + si] = sp;
      }
    }
  }
}

// --- k_post2: ids 0..4095 rmsnorm+rope (qkvh writeback); 4096..5119 vtr -----
__global__ __launch_bounds__(256) void k_post2(bf16* __restrict__ qkvh,
                                               const float* __restrict__ qnw, const float* __restrict__ knw,
                                               const float* __restrict__ ct, const float* __restrict__ stb,
                                               bf16* __restrict__ qa, bf16* __restrict__ ka,
                                               bf16* __restrict__ vt) {
  __shared__ short smem[8704];
  __shared__ float red[4];
  const int id = blockIdx.x, t = threadIdx.x;
  if (id < 4096) {
    float* buf = (float*)smem;
    const int token = id, b_ = token >> 11, si = token & 2047;
    bf16* base = qkvh + (size_t)token * 3 * cH;
    for (int pass = 0; pass < 2; ++pass) {
      __syncthreads();
      bf16* src = base + pass * cH;
      const float* nw = pass ? knw : qnw;
      float ss = 0.f;
      for (int i = t; i < cH; i += 256) {
        float v = b2f(src[i]);
        buf[i] = v;
        ss += v * v;
      }
      for (int d = 32; d; d >>= 1) ss += __shfl_down(ss, d);
      if ((t & 63) == 0) red[t >> 6] = ss;
      __syncthreads();
      const float rstd = rsqrtf((red[0] + red[1] + red[2] + red[3]) / cH + 1e-6f);
      for (int i = t; i < cH; i += 256) {
        float v = buf[i] * rstd * nw[i];
        buf[i] = v;
        src[i] = f2b(v);
      }
      __syncthreads();
      bf16* dst = pass ? ka : qa;
      const float scale = pass ? 1.f : cRSQRT_HD;
      const int hh = t >> 4, j0 = (t & 15) * 4;
      const float* cr = ct + (size_t)si * 64 + j0;
      const float* sr = stb + (size_t)si * 64 + j0;
      bf16* drow = dst + ((size_t)(b_ * cNH + hh) * cS + si) * cHD;
      unsigned short u1[4] __attribute__((aligned(8))), u2[4] __attribute__((aligned(8)));
#pragma unroll
      for (int i = 0; i < 4; ++i) {
        float x1 = buf[hh * cHD + j0 + i], x2 = buf[hh * cHD + 64 + j0 + i];
        u1[i] = f2bu((x1 * cr[i] - x2 * sr[i]) * scale);
        u2[i] = f2bu((x2 * cr[i] + x1 * sr[i]) * scale);
      }
      *(uint2*)(drow + j0) = *(uint2*)u1;
      *(uint2*)(drow + 64 + j0) = *(uint2*)u2;
    }
  } else {
    short* Ts = smem;  // 64*136
    const int id2 = id - 4096;
    const int tile = id2 & 31, h = (id2 >> 5) & 15, b_ = id2 >> 9;
    {
      const int r = t >> 2, seg = (t & 3) * 32;
      const bf16* src = qkvh + ((size_t)(b_ * cS) + tile * 64 + r) * 3 * cH + 2 * cH + h * cHD + seg;
      stage16(src, &Ts[r * 136 + seg]);
      stage16(src + 16, &Ts[r * 136 + seg + 16]);
    }
    __syncthreads();
    {
      const int d = t >> 1, seg2 = (t & 1) * 32;
      unsigned short u[32] __attribute__((aligned(16)));
#pragma unroll
      for (int i = 0; i < 32; ++i) u[i] = (unsigned short)Ts[(seg2 + i) * 136 + d];
      bf16* dp = vt + ((size_t)(b_ * cNH + h) * cHD + d) * cS + tile * 64 + seg2;
      *(uint4*)dp = *(uint4*)u;
      *(uint4*)(dp + 8) = *(uint4*)(u + 8);
      *(uint4*)(dp + 16) = *(uint4*)(u + 16);
      *(uint4*)(dp + 24) = *(uint4*)(u + 24);
    }
  }
}

// --- k_mid: ids 0..4095 fq/fk/fv from qkvh; 4096..7167 mirror cvt;
//            7168..7679 w1t init (transpose of fp32 master w1s) ---
__global__ __launch_bounds__(256) void k_mid(const bf16* __restrict__ qkvh,
                                             const float* __restrict__ qk_scale,
                                             const float* __restrict__ qk_offset,
                                             bf16* fq, bf16* fk, bf16* fv,
                                             const float* __restrict__ w0s_, bf16* __restrict__ w0b_,
                                             const float* __restrict__ w1s_, bf16* __restrict__ w1t_) {
  __shared__ short Ts[64 * 72];
  const int id = blockIdx.x, t = threadIdx.x;
  if (id < 4096) {
    const int token = id, b_ = token >> 11, si = token & 2047;
    const bf16* base = qkvh + (size_t)token * 3 * cH;
#pragma unroll
    for (int pass = 0; pass < 2; ++pass) {
      const bf16* src = base + pass * cH;
      bf16* fdst = pass ? fk : fq;
      const int head = t >> 6, lane = t & 63;
      float f[8];
      float ss2 = 0.f;
#pragma unroll
      for (int k = 0; k < 8; ++k) {
        const int idx = head * cFD + lane + k * 64;
        float v = b2f(src[idx]);
        float u = v * qk_scale[idx * 2 + pass] + qk_offset[idx * 2 + pass];
        float fv_ = u * sigmoidf_(u);
        f[k] = fv_;
        ss2 += fv_ * fv_;
      }
      for (int d = 1; d < 64; d <<= 1) ss2 += __shfl_xor(ss2, d);
      const float sc2 = rsqrtf(ss2 + 1e-12f);
      bf16* dst = fdst + ((size_t)(b_ * cNFW + head) * cS + si) * cFD;
#pragma unroll
      for (int k = 0; k < 8; ++k) dst[lane + k * 64] = f2b(f[k] * sc2);
    }
    const bf16* vr = base + 2 * cH;
    for (int i = t; i < cH; i += 256) {
      float v = b2f(vr[i]);
      fv[((size_t)(b_ * cNFW + (i >> 9)) * cS + si) * cFD + (i & 511)] = f2b(v * sigmoidf_(v));
    }
  } else if (id < 7168) {
    const size_t i = ((size_t)(id - 4096) * 256 + t) * 8;
    float4 a = *(const float4*)(w0s_ + i), b = *(const float4*)(w0s_ + i + 4);
    unsigned short u[8] __attribute__((aligned(16)));
    u[0] = f2bu(a.x); u[1] = f2bu(a.y); u[2] = f2bu(a.z); u[3] = f2bu(a.w);
    u[4] = f2bu(b.x); u[5] = f2bu(b.y); u[6] = f2bu(b.z); u[7] = f2bu(b.w);
    *(uint4*)(w0b_ + i) = *(uint4*)u;
  } else {
    const int id3 = id - 7168;
    const int bh = id3 >> 6, tile = id3 & 63, by = tile >> 3, bx = tile & 7;
    {
      const int rr = t >> 2, cseg = (t & 3) * 16;
      const float* p = w1s_ + (size_t)bh * ZL_ + (size_t)(by * 64 + rr) * cFD + bx * 64 + cseg;
      unsigned short u[16] __attribute__((aligned(16)));
#pragma unroll
      for (int i = 0; i < 16; ++i) u[i] = f2bu(p[i]);
      *(uint4*)&Ts[rr * 72 + cseg] = *(uint4*)u;
      *(uint4*)&Ts[rr * 72 + cseg + 8] = *(uint4*)(u + 8);
    }
    __syncthreads();
    {
      const int oc_ = t >> 2, rseg = (t & 3) * 16;
      unsigned short u[16] __attribute__((aligned(16)));
#pragma unroll
      for (int i = 0; i < 16; ++i) u[i] = (unsigned short)Ts[(rseg + i) * 72 + oc_];
      bf16* dp = w1t_ + (size_t)bh * ZL_ + (size_t)(bx * 64 + oc_) * cFD + by * 64 + rseg;
      *(uint4*)dp = *(uint4*)u;
      *(uint4*)(dp + 8) = *(uint4*)(u + 8);
    }
  }
}

// -- attention: 128-row q blocks, 8 waves, paired tiles, XCD swizzle ---------
__global__ __launch_bounds__(512) void k_attn6(const bf16* __restrict__ qa, const bf16* __restrict__ ka,
                                               const bf16* __restrict__ vt, bf16* __restrict__ y) {
  const int id = blockIdx.x;
  const int xcd = id & 7;
  const int j = id >> 3;
  const int p = j & 7;
  const int hb = (j >> 3) * 8 + xcd;
  const int h = hb & 15, b_ = hb >> 4;
  __shared__ short KsP[9216];
  __shared__ short Vts[128 * 72];
  const int t = threadIdx.x, lane = t & 63, g = lane >> 4, c16 = lane & 15, wv = t >> 6;
  const size_t hbq = (size_t)(b_ * cNH + h) * cS;
  const bf16* vb = vt + (size_t)(b_ * cNH + h) * (size_t)(cHD * cS);
  const int r = t >> 3, seg = (t & 7) * 16;
  const int dv = t >> 2, seg2 = (t & 3) * 16;
  const f32x4 zero4 = {0.f, 0.f, 0.f, 0.f};

  for (int half = 0; half < 2; ++half) {
    const int qt = half ? p : 15 - p;
    const int q0 = qt * 128;
    const int nkt = 2 * qt + 2;
    short8 qf[4];
    {
      const bf16* qsrc = qa + (hbq + q0 + wv * 16 + c16) * cHD;
#pragma unroll
      for (int ks = 0; ks < 4; ++ks) qf[ks] = *(const short8*)(qsrc + ks * 32 + g * 8);
    }
    f32x4 o[8];
#pragma unroll
    for (int i = 0; i < 8; ++i) o[i] = zero4;
    float m[4], l[4];
#pragma unroll
    for (int rr = 0; rr < 4; ++rr) { m[rr] = -1e30f; l[rr] = 0.f; }

    uint4 kp0, kp1, vp0, vp1;
    {
      const bf16* ksrc = ka + (hbq + r) * cHD + seg;
      kp0 = *(const uint4*)ksrc; kp1 = *(const uint4*)(ksrc + 8);
      const bf16* vsrc = vb + (size_t)dv * cS + seg2;
      vp0 = *(const uint4*)vsrc; vp1 = *(const uint4*)(vsrc + 8);
    }

    for (int kt = 0; kt < nkt; ++kt) {
      __syncthreads();
      {
        short* kd = &KsP[r * 136 + seg];
        *(uint4*)kd = kp0; *(uint4*)(kd + 8) = kp1;
        short* vd = &Vts[dv * 72 + seg2];
        *(uint4*)vd = vp0; *(uint4*)(vd + 8) = vp1;
      }
      __syncthreads();
      if (kt + 1 < nkt) {
        const bf16* ksrc = ka + (hbq + (kt + 1) * 64 + r) * cHD + seg;
        kp0 = *(const uint4*)ksrc; kp1 = *(const uint4*)(ksrc + 8);
        const bf16* vsrc = vb + (size_t)dv * cS + (kt + 1) * 64 + seg2;
        vp0 = *(const uint4*)vsrc; vp1 = *(const uint4*)(vsrc + 8);
      } else if (half == 0) {
        const bf16* ksrc = ka + (hbq + r) * cHD + seg;
        kp0 = *(const uint4*)ksrc; kp1 = *(const uint4*)(ksrc + 8);
        const bf16* vsrc = vb + (size_t)dv * cS + seg2;
        vp0 = *(const uint4*)vsrc; vp1 = *(const uint4*)(vsrc + 8);
      }

      f32x4 s4[4];
#pragma unroll
      for (int ni = 0; ni < 4; ++ni) s4[ni] = zero4;
      __builtin_amdgcn_s_setprio(1);
#pragma unroll
      for (int ks = 0; ks < 4; ++ks) {
#pragma unroll
        for (int ni = 0; ni < 4; ++ni) {
          short8 bb = *(const short8*)&KsP[(ni * 16 + c16) * 136 + ks * 32 + g * 8];
          s4[ni] = __builtin_amdgcn_mfma_f32_16x16x32_bf16(qf[ks], bb, s4[ni], 0, 0, 0);
        }
      }
      __builtin_amdgcn_s_setprio(0);
      __syncthreads();
      if (kt * 64 + 64 > q0) {
#pragma unroll
        for (int ni = 0; ni < 4; ++ni) {
          const int kv = kt * 64 + ni * 16 + c16;
#pragma unroll
          for (int rr = 0; rr < 4; ++rr) {
            const int qr = q0 + wv * 16 + g * 4 + rr;
            if (kv > qr) s4[ni][rr] = -1e9f;
          }
        }
      }
      float mx[4];
#pragma unroll
      for (int rr = 0; rr < 4; ++rr)
        mx[rr] = fmaxf(fmaxf(s4[0][rr], s4[1][rr]), fmaxf(s4[2][rr], s4[3][rr]));
#pragma unroll
      for (int d = 1; d < 16; d <<= 1)
#pragma unroll
        for (int rr = 0; rr < 4; ++rr) mx[rr] = fmaxf(mx[rr], __shfl_xor(mx[rr], d));
      bool need = false;
#pragma unroll
      for (int rr = 0; rr < 4; ++rr) need |= (mx[rr] > m[rr] + 8.f);
      if (__any(need)) {
        float corr[4];
#pragma unroll
        for (int rr = 0; rr < 4; ++rr) {
          float mn = fmaxf(m[rr], mx[rr]);
          corr[rr] = __expf(m[rr] - mn);
          m[rr] = mn;
        }
#pragma unroll
        for (int rr = 0; rr < 4; ++rr) l[rr] *= corr[rr];
#pragma unroll
        for (int nf = 0; nf < 8; ++nf)
#pragma unroll
          for (int rr = 0; rr < 4; ++rr) o[nf][rr] *= corr[rr];
      }
      float psum[4] = {0.f, 0.f, 0.f, 0.f};
#pragma unroll
      for (int ni = 0; ni < 4; ++ni)
#pragma unroll
        for (int rr = 0; rr < 4; ++rr) {
          float pp = __expf(s4[ni][rr] - m[rr]);
          s4[ni][rr] = pp;
          psum[rr] += pp;
        }
#pragma unroll
      for (int d = 1; d < 16; d <<= 1)
#pragma unroll
        for (int rr = 0; rr < 4; ++rr) psum[rr] += __shfl_xor(psum[rr], d);
#pragma unroll
      for (int rr = 0; rr < 4; ++rr) l[rr] += psum[rr];
      short* pw = &KsP[wv * 1152];
#pragma unroll
      for (int ni = 0; ni < 4; ++ni)
#pragma unroll
        for (int rr = 0; rr < 4; ++rr)
          pw[(g * 4 + rr) * 72 + ni * 16 + c16] = (short)f2bu(s4[ni][rr]);
      __builtin_amdgcn_s_setprio(1);
#pragma unroll
      for (int ks2 = 0; ks2 < 2; ++ks2) {
        short8 a = *(const short8*)&pw[c16 * 72 + ks2 * 32 + g * 8];
#pragma unroll
        for (int nf = 0; nf < 8; ++nf) {
          short8 bb = *(const short8*)&Vts[(nf * 16 + c16) * 72 + ks2 * 32 + g * 8];
          o[nf] = __builtin_amdgcn_mfma_f32_16x16x32_bf16(a, bb, o[nf], 0, 0, 0);
        }
      }
      __builtin_amdgcn_s_setprio(0);
    }
    float inv[4];
#pragma unroll
    for (int rr = 0; rr < 4; ++rr) inv[rr] = 1.f / l[rr];
#pragma unroll
    for (int nf = 0; nf < 8; ++nf)
#pragma unroll
      for (int rr = 0; rr < 4; ++rr) {
        const size_t row = (size_t)(b_ * cS) + q0 + wv * 16 + g * 4 + rr;
        y[row * cH + h * cHD + nf * 16 + c16] = f2b(o[nf][rr] * inv[rr]);
      }
  }
}

}  // namespace

extern "C" void kernel_launch(void* const* d_in, const int* in_sizes, int n_in,
                              void* d_out, int out_size, void* d_ws, size_t ws_size,
                              hipStream_t stream) {
  (void)in_sizes; (void)n_in; (void)out_size; (void)ws_size;
  const float* x         = (const float*)d_in[0];
  const float* qkv_w     = (const float*)d_in[1];
  const float* q_norm_w  = (const float*)d_in[2];
  const float* k_norm_w  = (const float*)d_in[3];
  const float* qk_scale  = (const float*)d_in[4];
  const float* qk_offset = (const float*)d_in[5];
  const float* lr_w      = (const float*)d_in[6];
  const float* lr_b      = (const float*)d_in[7];
  const float* w0        = (const float*)d_in[8];
  const float* w1        = (const float*)d_in[9];
  const float* w2        = (const float*)d_in[10];
  const float* ttt_nw    = (const float*)d_in[11];
  const float* o_proj_w  = (const float*)d_in[12];
  float* out = (float*)d_out;

  // ---- workspace layout (bytes), total 143,851,520 (proven footprint) ----
  char* Wb = (char*)d_ws;
  bf16* qkvh = (bf16*)Wb;                 // phase-1 only (50.3MB)
  bf16* hq   = (bf16*)(Wb + 0UL);         // TTT phase buffers:
  bf16* trH  = (bf16*)(Wb + 4194304UL);
  bf16* trD1 = (bf16*)(Wb + 8388608UL);
  bf16* trD2 = (bf16*)(Wb + 12582912UL);
  bf16* trK  = (bf16*)(Wb + 16777216UL);
  bf16* trV  = (bf16*)(Wb + 20971520UL);
  bf16* occ  = (bf16*)(Wb + 25165824UL);
  bf16* w1t  = (bf16*)(Wb + 29360128UL);  // transposed w1 mirror
  bf16* w0b  = (bf16*)(Wb + 33554432UL);  // contiguous mirrors w0b,w1b0,w2b
  bf16* w1b0 = (bf16*)(Wb + 37748736UL);
  bf16* w2b  = (bf16*)(Wb + 41943040UL);
  bf16* w1b1 = (bf16*)(Wb + 46137344UL);  // w1 row-major mirror ping-pong
  bf16* opwb = (bf16*)(Wb + 0UL);         // after TTT loop
  size_t off = 50331648UL;
  bf16* fqb = (bf16*)(Wb + off); off += 16777216UL;
  bf16* fkb = (bf16*)(Wb + off); off += 16777216UL;
  bf16* fvb = (bf16*)(Wb + off); off += 16777216UL;
  float* w0s = (float*)(Wb + off); off += 8388608UL;
  float* w1s = (float*)(Wb + off); off += 8388608UL;
  float* w2s = (float*)(Wb + off); off += 8388608UL;
  float* lr0 = (float*)(Wb + off); off += 65536UL;
  float* lr1 = (float*)(Wb + off); off += 65536UL;
  float* lr2 = (float*)(Wb + off); off += 65536UL;
  bf16* y = (bf16*)(Wb + off); off += 16777216UL;
  float* ct  = (float*)(Wb + off); off += 524288UL;
  float* stb = (float*)(Wb + off); off += 524288UL;
  bf16* xb = fqb;
  bf16* qkvwb = fkb;
  bf16* qa = fqb;
  bf16* ka = fkb;
  bf16* vt = fvb;
  bf16* w1m[2] = {w1b0, w1b1};

  const float base_lr_inv = logf(expm1f(0.001f));
  dim3 blk(256);

  k_prep<<<dim3(20992), blk, 0, stream>>>(x, qkv_w, w0, w1, w2, lr_w, lr_b,
                                          xb, qkvwb, w0s, w1s, w2s, ct, stb,
                                          lr0, lr1, lr2, base_lr_inv);
  k_mm8<bf16><<<dim3(48, 16), dim3(512), 0, stream>>>(xb, 2048, qkvwb, 2048, qkvh, 6144, 2048);
  k_post2<<<dim3(5120), blk, 0, stream>>>(qkvh, q_norm_w, k_norm_w, ct, stb, qa, ka, vt);
  k_attn6<<<dim3(256), dim3(512), 0, stream>>>(qa, ka, vt, y);
  // fq/fk/fv overwrite qa/ka/vt after attn; mirrors + w1t init in same launch
  k_mid<<<dim3(7680), blk, 0, stream>>>(qkvh, qk_scale, qk_offset, fqb, fkb, fvb,
                                        w0s, w0b, w1s, w1t);

  for (int c = 0; c < 4; ++c) {
    const int g1 = (c == 0) ? 1536 : 5632;
    k_fuse1<<<dim3(g1), blk, 0, stream>>>(fqb, fkb, fvb, w0b, w1t, w2b,
                                          hq, trH, trD1, trD2, trK, trV,
                                          lr0, lr1, lr2, occ, ttt_nw, y, c);
    k_updna<<<dim3(512), blk, 0, stream>>>(trV, trH, trD1, trD2, trK, hq, w1m[c & 1],
                                           w0s, w1s, w2s, w0b, w1m[(c + 1) & 1], w2b, w1t,
                                           occ);
  }
  k_normcvt<<<dim3(6144), blk, 0, stream>>>(occ, ttt_nw, y, o_proj_w, opwb, 3);
  k_mm8<float><<<dim3(16, 16), dim3(512), 0, stream>>>(y, 2048, opwb, 2048, out, 2048, 2048);
}

// Round 19
// 658.943 us; speedup vs baseline: 1.2430x; 1.2430x over previous
//
#include <hip/hip_runtime.h>
#include <hip/hip_bf16.h>
#include <math.h>

using bf16 = __hip_bfloat16;

namespace {

constexpr int cH = 2048;
constexpr int cNH = 16;
constexpr int cHD = 128;
constexpr int cNFW = 4;
constexpr int cFD = 512;
constexpr int cS = 2048;
constexpr float cRSQRT_HD = 0.08838834764831845f;  // 1/sqrt(128)
constexpr long ZL_ = 262144;   // 512*512
constexpr long ZG_ = 1048576;  // 2048*512

typedef __attribute__((ext_vector_type(8))) short short8;
typedef __attribute__((ext_vector_type(4))) float f32x4;

__device__ __forceinline__ float sigmoidf_(float x) { return 1.0f / (1.0f + __expf(-x)); }
__device__ __forceinline__ float b2f(bf16 v) { return __bfloat162float(v); }
__device__ __forceinline__ bf16 f2b(float v) { return __float2bfloat16(v); }
__device__ __forceinline__ unsigned short f2bu(float f) {
  return __builtin_bit_cast(unsigned short, __float2bfloat16(f));
}
__device__ __forceinline__ float bu2f(unsigned u) { return __uint_as_float(u << 16); }

#if defined(__has_builtin)
#if __has_builtin(__builtin_amdgcn_global_load_lds)
#define HAVE_GLOAD 1
#endif
#endif

__device__ __forceinline__ void gload16(const bf16* g, short* ldsbase) {
#ifdef HAVE_GLOAD
  __builtin_amdgcn_global_load_lds((const __attribute__((address_space(1))) void*)g,
                                   (__attribute__((address_space(3))) void*)ldsbase, 16, 0, 0);
#else
  const int l = threadIdx.x & 63;
  *(uint4*)(ldsbase + l * 8) = *(const uint4*)g;
#endif
}

__device__ __forceinline__ void stage16(const bf16* src, short* dst) {
  *(uint4*)dst = *(const uint4*)src;
  *(uint4*)(dst + 8) = *(const uint4*)(src + 8);
}

__device__ __forceinline__ void store1(float* p, float v) { *p = v; }
__device__ __forceinline__ void store1(bf16* p, float v) { *p = f2b(v); }

// ---------------------------------------------------------------------------
// MFMA NT GEMM core: 128x128 tile, 4 waves (2x2 of 64x64), BK=32, linear LDS.
// (used by fuse1/updna TTT kernels)
// ---------------------------------------------------------------------------
__device__ __forceinline__ void mm_core32(const bf16* __restrict__ Ab, int lda,
                                          const bf16* __restrict__ Bb, int ldb, int K,
                                          short* As, short* Bs, f32x4 acc[4][4]) {
  const int t = threadIdx.x, lane = t & 63, g = lane >> 4, c16 = lane & 15;
  const int wv = t >> 6, wm = (wv >> 1) * 64, wn = (wv & 1) * 64;
  for (int k0 = 0; k0 < K; k0 += 32) {
    __syncthreads();
    {
      const int ch = wv * 2;
      const bf16* ga = Ab + (size_t)(ch * 16 + (lane >> 2)) * lda + k0 + (lane & 3) * 8;
      gload16(ga, &As[ch * 512]);
      gload16(ga + (size_t)16 * lda, &As[ch * 512 + 512]);
      const bf16* gb = Bb + (size_t)(ch * 16 + (lane >> 2)) * ldb + k0 + (lane & 3) * 8;
      gload16(gb, &Bs[ch * 512]);
      gload16(gb + (size_t)16 * ldb, &Bs[ch * 512 + 512]);
    }
    __syncthreads();
    short8 af[4], bfr[4];
#pragma unroll
    for (int mi = 0; mi < 4; ++mi) af[mi] = *(const short8*)&As[(wm + mi * 16 + c16) * 32 + g * 8];
#pragma unroll
    for (int ni = 0; ni < 4; ++ni) bfr[ni] = *(const short8*)&Bs[(wn + ni * 16 + c16) * 32 + g * 8];
#pragma unroll
    for (int mi = 0; mi < 4; ++mi)
#pragma unroll
      for (int ni = 0; ni < 4; ++ni)
        acc[mi][ni] = __builtin_amdgcn_mfma_f32_16x16x32_bf16(af[mi], bfr[ni], acc[mi][ni], 0, 0, 0);
  }
}

template <bool ACC, bool MIR, typename TC>
__device__ __forceinline__ void mm_store(TC* Cb, bf16* Mb, int ldc, int rb, int cb, f32x4 acc[4][4]) {
  const int t = threadIdx.x, lane = t & 63, g = lane >> 4, c16 = lane & 15;
  const int wv = t >> 6, wm = (wv >> 1) * 64, wn = (wv & 1) * 64;
  const int rbase = rb + wm, cbase = cb + wn;
#pragma unroll
  for (int mi = 0; mi < 4; ++mi)
#pragma unroll
    for (int ni = 0; ni < 4; ++ni) {
      const int col = cbase + ni * 16 + c16;
#pragma unroll
      for (int r = 0; r < 4; ++r) {
        const int row = rbase + mi * 16 + g * 4 + r;
        TC* cp = Cb + (size_t)row * ldc + col;
        if constexpr (ACC) {
          float nv = *cp + acc[mi][ni][r];
          *cp = nv;
          if constexpr (MIR) Mb[(size_t)row * ldc + col] = f2b(nv);
        } else {
          store1(cp, acc[mi][ni][r]);
        }
      }
    }
}

// ---------------------------------------------------------------------------
// Pipelined GEMM: 256(M)x128(N) tile, 8 waves (4Mx2N), BK=64, counted vmcnt,
// chunk-XOR LDS swizzle, 3-deep buffer rotation, ONE barrier per K-tile.
// Per phase: 16 ds_read(buf kt%3) | 6 gload(tile kt+2 -> buf (kt+2)%3) |
//            32 MFMA | vmcnt(6) | s_barrier.  K%64==0, M%256==0, N%128==0.
// ---------------------------------------------------------------------------
template <typename TC>
__global__ __launch_bounds__(512, 1) void k_mm8(const bf16* __restrict__ A, int lda,
                                                const bf16* __restrict__ B, int ldb,
                                                TC* __restrict__ C, int ldc, int K) {
  __shared__ short LA[3][256 * 64];  // 96 KB
  __shared__ short LB[3][128 * 64];  // 48 KB
  const int t = threadIdx.x, lane = t & 63, wv = t >> 6;
  const int g = lane >> 4, c16 = lane & 15;
  const int wm = (wv >> 1) * 64, wn = (wv & 1) * 64;
  const bf16* Ab = A + (size_t)blockIdx.y * 256 * lda;
  const bf16* Bb = B + (size_t)blockIdx.x * 128 * ldb;
  const int NKT = K >> 6;
  const int srow = wv * 16 + (lane >> 3);
  // source-permuted column: LDS slot (r, c) receives global chunk c ^ (r&7)
  const int scol = ((lane & 7) ^ ((lane >> 3) & 7)) * 8;

  auto stA = [&](int buf, int half, int kt) {
    const int ktc = (kt < NKT) ? kt : 0;  // clamp: garbage into dead slot
    const bf16* src = Ab + (size_t)(half * 128 + srow) * lda + ktc * 64 + scol;
    short* dst = &LA[buf][(half * 128 + wv * 16) * 64];
    gload16(src, dst);
    gload16(src + (size_t)8 * lda, dst + 512);
  };
  auto stB = [&](int buf, int kt) {
    const int ktc = (kt < NKT) ? kt : 0;
    const bf16* src = Bb + (size_t)srow * ldb + ktc * 64 + scol;
    short* dst = &LB[buf][(wv * 16) * 64];
    gload16(src, dst);
    gload16(src + (size_t)8 * ldb, dst + 512);
  };

  f32x4 acc[4][4];
  const f32x4 zero4 = {0.f, 0.f, 0.f, 0.f};
#pragma unroll
  for (int i = 0; i < 4; ++i)
#pragma unroll
    for (int j = 0; j < 4; ++j) acc[i][j] = zero4;

  // prologue: tiles 0 and 1 into bufs 0 and 1 (6 loads/lane each)
  stA(0, 0, 0); stA(0, 1, 0); stB(0, 0);
  stA(1, 0, 1); stA(1, 1, 1); stB(1, 1);
  asm volatile("s_waitcnt vmcnt(6)" ::: "memory");  // tile0 landed
  __builtin_amdgcn_s_barrier();

  for (int kt = 0; kt < NKT; ++kt) {
    const int cb = kt % 3, nb = (kt + 2) % 3;
    short8 af[4][2], bfr[4][2];
#pragma unroll
    for (int f = 0; f < 4; ++f)
#pragma unroll
      for (int kk = 0; kk < 2; ++kk) {
        const int ra = wm + f * 16 + c16;
        af[f][kk] = *(const short8*)&LA[cb][ra * 64 + ((kk * 4 + g) ^ (ra & 7)) * 8];
        const int rb_ = wn + f * 16 + c16;
        bfr[f][kk] = *(const short8*)&LB[cb][rb_ * 64 + ((kk * 4 + g) ^ (rb_ & 7)) * 8];
      }
    // stage tile kt+2 into buf nb (last read in phase kt-1; free by barrier)
    stA(nb, 0, kt + 2); stA(nb, 1, kt + 2); stB(nb, kt + 2);
    __builtin_amdgcn_s_setprio(1);
#pragma unroll
    for (int f = 0; f < 4; ++f)
#pragma unroll
      for (int ni = 0; ni < 4; ++ni)
#pragma unroll
        for (int kk = 0; kk < 2; ++kk)
          acc[f][ni] = __builtin_amdgcn_mfma_f32_16x16x32_bf16(
              af[f][kk], bfr[ni][kk], acc[f][ni], 0, 0, 0);
    __builtin_amdgcn_s_setprio(0);
    asm volatile("s_waitcnt vmcnt(6)" ::: "memory");  // tile kt+1 landed
    __builtin_amdgcn_s_barrier();
  }

  const int rbase = blockIdx.y * 256 + wm, cbase = blockIdx.x * 128 + wn;
#pragma unroll
  for (int fr = 0; fr < 4; ++fr)
#pragma unroll
    for (int ni = 0; ni < 4; ++ni) {
      const int col = cbase + ni * 16 + c16;
#pragma unroll
      for (int r = 0; r < 4; ++r)
        store1(C + (size_t)(rbase + fr * 16 + g * 4 + r) * ldc + col, acc[fr][ni][r]);
    }
}

// ---------------------------------------------------------------------------
// Fused stage1 + gates + (trK,trV transposes) + (prev-chunk norm-add).
// ---------------------------------------------------------------------------
__global__ __launch_bounds__(256) void k_fuse1(const bf16* __restrict__ fq, const bf16* __restrict__ fk,
                                               const bf16* __restrict__ fv,
                                               const bf16* __restrict__ w0b, const bf16* __restrict__ w1t,
                                               const bf16* __restrict__ w2b,
                                               bf16* __restrict__ hq, bf16* __restrict__ trH,
                                               bf16* __restrict__ trD1, bf16* __restrict__ trD2,
                                               bf16* __restrict__ trK, bf16* __restrict__ trV,
                                               const float* __restrict__ lr0, const float* __restrict__ lr1,
                                               const float* __restrict__ lr2,
                                               const bf16* __restrict__ occ,
                                               const float* __restrict__ tw, bf16* __restrict__ y,
                                               int chunk) {
  __shared__ short S[12288];
  __shared__ float red[4];
  const int id = blockIdx.x, t = threadIdx.x;
  const size_t choff = (size_t)chunk * 262144;

  if (id < 512) {
    const int bh = id >> 6, tile = id & 63, by = tile >> 3, bx = tile & 7;
    const int lane = t & 63, g = lane >> 4, c16 = lane & 15, wv = t >> 6;
    const int wm = (wv >> 1) * 32, wn = (wv & 1) * 32;
    const bf16* Aq = fq + (size_t)bh * ZG_ + choff + (size_t)(by * 64) * cFD;
    const bf16* Ak = fk + (size_t)bh * ZG_ + choff + (size_t)(by * 64) * cFD;
    const bf16* Av = fv + (size_t)bh * ZG_ + choff + (size_t)(by * 64) * cFD;
    const bf16* B0 = w0b + (size_t)bh * ZL_ + (size_t)(bx * 64) * cFD;
    const bf16* B2 = w2b + (size_t)bh * ZL_ + (size_t)(bx * 64) * cFD;
    const bf16* B1 = w1t + (size_t)bh * ZL_ + (size_t)(bx * 64) * cFD;  // [e][d]

    f32x4 acc[5][2][2];
    const f32x4 zero4 = {0.f, 0.f, 0.f, 0.f};
#pragma unroll
    for (int v = 0; v < 5; ++v)
#pragma unroll
      for (int i = 0; i < 2; ++i)
#pragma unroll
        for (int j = 0; j < 2; ++j) acc[v][i][j] = zero4;

    const int srow = wv * 16 + (lane >> 2), scol = (lane & 3) * 8;
    for (int k0 = 0; k0 < 512; k0 += 32) {
      __syncthreads();
      gload16(Aq + (size_t)srow * cFD + k0 + scol, &S[0 + wv * 512]);
      gload16(Ak + (size_t)srow * cFD + k0 + scol, &S[2048 + wv * 512]);
      gload16(Av + (size_t)srow * cFD + k0 + scol, &S[4096 + wv * 512]);
      gload16(B0 + (size_t)srow * cFD + k0 + scol, &S[6144 + wv * 512]);
      gload16(B2 + (size_t)srow * cFD + k0 + scol, &S[8192 + wv * 512]);
      gload16(B1 + (size_t)srow * cFD + k0 + scol, &S[10240 + wv * 512]);
      __syncthreads();
      short8 aq[2], ak[2], av[2], b0[2], b2[2], b1[2];
#pragma unroll
      for (int mi = 0; mi < 2; ++mi) {
        const int ro = (wm + mi * 16 + c16) * 32 + g * 8;
        aq[mi] = *(const short8*)&S[0 + ro];
        ak[mi] = *(const short8*)&S[2048 + ro];
        av[mi] = *(const short8*)&S[4096 + ro];
      }
#pragma unroll
      for (int ni = 0; ni < 2; ++ni) {
        const int ro = (wn + ni * 16 + c16) * 32 + g * 8;
        b0[ni] = *(const short8*)&S[6144 + ro];
        b2[ni] = *(const short8*)&S[8192 + ro];
        b1[ni] = *(const short8*)&S[10240 + ro];
      }
#pragma unroll
      for (int mi = 0; mi < 2; ++mi)
#pragma unroll
        for (int ni = 0; ni < 2; ++ni) {
          acc[0][mi][ni] = __builtin_amdgcn_mfma_f32_16x16x32_bf16(aq[mi], b0[ni], acc[0][mi][ni], 0, 0, 0);
          acc[1][mi][ni] = __builtin_amdgcn_mfma_f32_16x16x32_bf16(aq[mi], b2[ni], acc[1][mi][ni], 0, 0, 0);
          acc[2][mi][ni] = __builtin_amdgcn_mfma_f32_16x16x32_bf16(ak[mi], b0[ni], acc[2][mi][ni], 0, 0, 0);
          acc[3][mi][ni] = __builtin_amdgcn_mfma_f32_16x16x32_bf16(ak[mi], b2[ni], acc[3][mi][ni], 0, 0, 0);
          acc[4][mi][ni] = __builtin_amdgcn_mfma_f32_16x16x32_bf16(av[mi], b1[ni], acc[4][mi][ni], 0, 0, 0);
        }
    }

    float l0v[2][4], l2v[2][4];
#pragma unroll
    for (int mi = 0; mi < 2; ++mi)
#pragma unroll
      for (int r = 0; r < 4; ++r) {
        const int row = by * 64 + wm + mi * 16 + g * 4 + r;
        l0v[mi][r] = lr0[bh * 2048 + chunk * 512 + row];
        l2v[mi][r] = lr2[bh * 2048 + chunk * 512 + row];
      }
#pragma unroll
    for (int mi = 0; mi < 2; ++mi)
#pragma unroll
      for (int ni = 0; ni < 2; ++ni)
#pragma unroll
        for (int r = 0; r < 4; ++r) {
          float hq1 = acc[0][mi][ni][r], hq2 = acc[1][mi][ni][r];
          float g1 = acc[2][mi][ni][r], g2 = acc[3][mi][ni][r], dh = acc[4][mi][ni][r];
          acc[0][mi][ni][r] = hq1 * sigmoidf_(hq1) * hq2;
          float sg = sigmoidf_(g1);
          float gate = g1 * sg;
          acc[1][mi][ni][r] = gate * g2;
          acc[2][mi][ni][r] = l0v[mi][r] * dh * g2 * (sg * (1.0f + g1 * (1.0f - sg)));
          acc[3][mi][ni][r] = l2v[mi][r] * dh * gate;
        }

    short* Ts = S;
    bf16* dst0 = hq + (size_t)bh * ZL_;
    bf16* dstT[3] = {trH + (size_t)bh * ZL_, trD1 + (size_t)bh * ZL_, trD2 + (size_t)bh * ZL_};
#pragma unroll
    for (int rd = 0; rd < 4; ++rd) {
      __syncthreads();
#pragma unroll
      for (int mi = 0; mi < 2; ++mi)
#pragma unroll
        for (int ni = 0; ni < 2; ++ni)
#pragma unroll
          for (int r = 0; r < 4; ++r) {
            const int row = wm + mi * 16 + g * 4 + r, col = wn + ni * 16 + c16;
            if (rd == 0) Ts[row * 66 + col] = (short)f2bu(acc[0][mi][ni][r]);
            else Ts[col * 66 + row] = (short)f2bu(acc[rd][mi][ni][r]);
          }
      __syncthreads();
      const int rr = t >> 2, cs = (t & 3) * 16;
      unsigned short u[16] __attribute__((aligned(16)));
#pragma unroll
      for (int i = 0; i < 16; ++i) u[i] = (unsigned short)Ts[rr * 66 + cs + i];
      bf16* dp = (rd == 0) ? (dst0 + (size_t)(by * 64 + rr) * cFD + bx * 64 + cs)
                           : (dstT[rd - 1] + (size_t)(bx * 64 + rr) * cFD + by * 64 + cs);
      *(uint4*)dp = *(uint4*)u;
      *(uint4*)(dp + 8) = *(uint4*)(u + 8);
    }
  } else if (id < 1536) {
    short* Ts = S;  // 64*72
    const int id2 = id - 512;
    const int var = id2 >> 9, bh = (id2 >> 6) & 7, by = (id2 >> 3) & 7, bx = id2 & 7;
    const bf16* src = ((var == 0) ? fk : fv) + choff + (size_t)bh * ZG_;
    bf16* dst = ((var == 0) ? trK : trV) + (size_t)bh * ZL_;
    {
      const int rr = t >> 2, cseg = (t & 3) * 16;
      if (var == 0) {
        stage16(src + (size_t)(by * 64 + rr) * cFD + bx * 64 + cseg, &Ts[rr * 72 + cseg]);
      } else {
        const float s = lr1[bh * 2048 + chunk * 512 + by * 64 + rr];
        const bf16* p = src + (size_t)(by * 64 + rr) * cFD + bx * 64 + cseg;
        unsigned short u[16] __attribute__((aligned(16)));
#pragma unroll
        for (int i = 0; i < 16; ++i) u[i] = f2bu(b2f(p[i]) * s);
        *(uint4*)&Ts[rr * 72 + cseg] = *(uint4*)u;
        *(uint4*)&Ts[rr * 72 + cseg + 8] = *(uint4*)(u + 8);
      }
    }
    __syncthreads();
    {
      const int oc_ = t >> 2, rseg = (t & 3) * 16;
      unsigned short u[16] __attribute__((aligned(16)));
#pragma unroll
      for (int i = 0; i < 16; ++i) u[i] = (unsigned short)Ts[(rseg + i) * 72 + oc_];
      bf16* dp = dst + (size_t)(bx * 64 + oc_) * cFD + by * 64 + rseg;
      *(uint4*)dp = *(uint4*)u;
      *(uint4*)(dp + 8) = *(uint4*)(u + 8);
    }
  } else {
    const int rrow = id - 1536;
    const int bh = rrow >> 9, rr = rrow & 511;
    const bf16* src = occ + ((size_t)bh * 512 + rr) * 512;
    float v0 = b2f(src[t]), v1 = b2f(src[t + 256]);
    float ss = v0 * v0 + v1 * v1;
    for (int d = 32; d; d >>= 1) ss += __shfl_down(ss, d);
    if ((t & 63) == 0) red[t >> 6] = ss;
    __syncthreads();
    const float rstd = rsqrtf((red[0] + red[1] + red[2] + red[3]) / cFD + 1e-6f);
    const int si = (chunk - 1) * 512 + rr;
    bf16* dst = y + ((size_t)((bh >> 2) * cS) + si) * cH + (bh & 3) * cFD;
    dst[t] = f2b(b2f(dst[t]) + v0 * rstd * tw[t]);
    dst[t + 256] = f2b(b2f(dst[t + 256]) + v1 * rstd * tw[t + 256]);
  }
}

// ---------------------------------------------------------------------------
// updna: ids 0..383 weight-update GEMMs (var0 also writes w1t transposed);
//        ids 384..511 oc = hq @ w1_cur^T (128^2 tiles).
// ---------------------------------------------------------------------------
__global__ __launch_bounds__(256) void k_updna(const bf16* __restrict__ trV, const bf16* __restrict__ trH,
                                               const bf16* __restrict__ trD1, const bf16* __restrict__ trD2,
                                               const bf16* __restrict__ trK,
                                               const bf16* __restrict__ hq, const bf16* __restrict__ w1bc,
                                               float* w0s, float* w1s, float* w2s,
                                               bf16* w0b, bf16* w1bn, bf16* w2b, bf16* w1t,
                                               bf16* __restrict__ occ) {
  __shared__ short Sh[8704];
  const int id = blockIdx.x, t = threadIdx.x;
  const int lane = t & 63, g = lane >> 4, c16 = lane & 15, wv = t >> 6;
  if (id < 384) {
    short* As = Sh;
    short* Bs = Sh + 4096;
    const int z = id >> 4, tile = id & 15, by = tile >> 2, bx = tile & 3;
    const int var = z >> 3, bh = z & 7;
    const bf16 *Aa, *Bb;
    if (var == 0) {
      Aa = trV + (size_t)bh * ZL_ + (size_t)by * 128 * cFD;
      Bb = trH + (size_t)bh * ZL_ + (size_t)bx * 128 * cFD;
    } else if (var == 1) {
      Aa = trD1 + (size_t)bh * ZL_ + (size_t)by * 128 * cFD;
      Bb = trK + (size_t)bh * ZL_ + (size_t)bx * 128 * cFD;
    } else {
      Aa = trD2 + (size_t)bh * ZL_ + (size_t)by * 128 * cFD;
      Bb = trK + (size_t)bh * ZL_ + (size_t)bx * 128 * cFD;
    }
    f32x4 acc[4][4];
    const f32x4 zero4 = {0.f, 0.f, 0.f, 0.f};
#pragma unroll
    for (int i = 0; i < 4; ++i)
#pragma unroll
      for (int j = 0; j < 4; ++j) acc[i][j] = zero4;
    mm_core32(Aa, cFD, Bb, cFD, cFD, As, Bs, acc);
    if (var == 1) {
      mm_store<true, true>(w0s + (size_t)bh * ZL_, w0b + (size_t)bh * ZL_, cFD, by * 128, bx * 128, acc);
    } else if (var == 2) {
      mm_store<true, true>(w2s + (size_t)bh * ZL_, w2b + (size_t)bh * ZL_, cFD, by * 128, bx * 128, acc);
    } else {
      float* W = w1s + (size_t)bh * ZL_;
      bf16* M = w1bn + (size_t)bh * ZL_;
      const int wm = (wv >> 1) * 64, wn = (wv & 1) * 64;
#pragma unroll
      for (int mi = 0; mi < 4; ++mi)
#pragma unroll
        for (int ni = 0; ni < 4; ++ni) {
          const int col = bx * 128 + wn + ni * 16 + c16;
#pragma unroll
          for (int r = 0; r < 4; ++r) {
            const int row = by * 128 + wm + mi * 16 + g * 4 + r;
            float nv = W[(size_t)row * cFD + col] + acc[mi][ni][r];
            W[(size_t)row * cFD + col] = nv;
            M[(size_t)row * cFD + col] = f2b(nv);
            acc[mi][ni][r] = nv;
          }
        }
      bf16* T = w1t + (size_t)bh * ZL_;
      short* Ts = Sh;  // 64 cc x 136
#pragma unroll
      for (int rd = 0; rd < 2; ++rd) {
        __syncthreads();
        if (wn == rd * 64) {
#pragma unroll
          for (int mi = 0; mi < 4; ++mi)
#pragma unroll
            for (int ni = 0; ni < 4; ++ni) {
              const int cc = ni * 16 + c16;
              unsigned short u[4] __attribute__((aligned(8)));
#pragma unroll
              for (int r = 0; r < 4; ++r) u[r] = f2bu(acc[mi][ni][r]);
              *(uint2*)&Ts[cc * 136 + wm + mi * 16 + g * 4] = *(uint2*)u;
            }
        }
        __syncthreads();
        const int cc = t >> 2, seg = (t & 3) * 32;
        unsigned short u[32] __attribute__((aligned(16)));
#pragma unroll
        for (int i = 0; i < 32; ++i) u[i] = (unsigned short)Ts[cc * 136 + seg + i];
        bf16* dp = T + (size_t)(bx * 128 + rd * 64 + cc) * cFD + by * 128 + seg;
        *(uint4*)dp = *(uint4*)u;
        *(uint4*)(dp + 8) = *(uint4*)(u + 8);
        *(uint4*)(dp + 16) = *(uint4*)(u + 16);
        *(uint4*)(dp + 24) = *(uint4*)(u + 24);
      }
    }
  } else {
    short* As = Sh;
    short* Bs = Sh + 4096;
    const int id2 = id - 384;
    const int bh = id2 >> 4, tile = id2 & 15, by = tile >> 2, bx = tile & 3;
    const bf16* Aa = hq + (size_t)bh * ZL_ + (size_t)by * 128 * cFD;
    const bf16* Bb = w1bc + (size_t)bh * ZL_ + (size_t)bx * 128 * cFD;
    f32x4 acc[4][4];
    const f32x4 zero4 = {0.f, 0.f, 0.f, 0.f};
#pragma unroll
    for (int i = 0; i < 4; ++i)
#pragma unroll
      for (int j = 0; j < 4; ++j) acc[i][j] = zero4;
    mm_core32(Aa, cFD, Bb, cFD, cFD, As, Bs, acc);
    mm_store<false, false>(occ + (size_t)bh * ZL_, (bf16*)nullptr, cFD, by * 128, bx * 128, acc);
  }
}

// tail: ids 0..4095 final norm-add; 4096..6143 cvt o_proj_w -> opwb
__global__ __launch_bounds__(256) void k_normcvt(const bf16* __restrict__ occ,
                                                 const float* __restrict__ tw, bf16* __restrict__ y,
                                                 const float* __restrict__ opw, bf16* __restrict__ opwb,
                                                 int chunk) {
  __shared__ float red[4];
  const int id = blockIdx.x, t = threadIdx.x;
  if (id < 4096) {
    const int bh = id >> 9, rr = id & 511;
    const bf16* src = occ + ((size_t)bh * 512 + rr) * 512;
    float v0 = b2f(src[t]), v1 = b2f(src[t + 256]);
    float ss = v0 * v0 + v1 * v1;
    for (int d = 32; d; d >>= 1) ss += __shfl_down(ss, d);
    if ((t & 63) == 0) red[t >> 6] = ss;
    __syncthreads();
    const float rstd = rsqrtf((red[0] + red[1] + red[2] + red[3]) / cFD + 1e-6f);
    const int si = chunk * 512 + rr;
    bf16* dst = y + ((size_t)((bh >> 2) * cS) + si) * cH + (bh & 3) * cFD;
    dst[t] = f2b(b2f(dst[t]) + v0 * rstd * tw[t]);
    dst[t + 256] = f2b(b2f(dst[t + 256]) + v1 * rstd * tw[t + 256]);
  } else {
    const size_t i = ((size_t)(id - 4096) * 256 + t) * 8;
    float4 a = *(const float4*)(opw + i), b = *(const float4*)(opw + i + 4);
    unsigned short u[8] __attribute__((aligned(16)));
    u[0] = f2bu(a.x); u[1] = f2bu(a.y); u[2] = f2bu(a.z); u[3] = f2bu(a.w);
    u[4] = f2bu(b.x); u[5] = f2bu(b.y); u[6] = f2bu(b.z); u[7] = f2bu(b.w);
    *(uint4*)(opwb + i) = *(uint4*)u;
  }
}

// --- merged prep: cvt x, cvt qkv_w, winit (f4), rope table, lr projections --
__global__ __launch_bounds__(256) void k_prep(const float* __restrict__ x, const float* __restrict__ qkv_w,
                                              const float* __restrict__ w0, const float* __restrict__ w1,
                                              const float* __restrict__ w2,
                                              const float* __restrict__ lr_w, const float* __restrict__ lr_b,
                                              bf16* __restrict__ xb, bf16* __restrict__ qkvwb,
                                              float* __restrict__ w0s, float* __restrict__ w1s,
                                              float* __restrict__ w2s,
                                              float* __restrict__ ct, float* __restrict__ stb,
                                              float* lr0, float* lr1, float* lr2, float base) {
  __shared__ float xbuf[cH];
  const int id = blockIdx.x, t = threadIdx.x;
  if (id < 4096) {
    const size_t i = ((size_t)id * 256 + t) * 8;
    float4 a = *(const float4*)(x + i), b = *(const float4*)(x + i + 4);
    unsigned short u[8] __attribute__((aligned(16)));
    u[0] = f2bu(a.x); u[1] = f2bu(a.y); u[2] = f2bu(a.z); u[3] = f2bu(a.w);
    u[4] = f2bu(b.x); u[5] = f2bu(b.y); u[6] = f2bu(b.z); u[7] = f2bu(b.w);
    *(uint4*)(xb + i) = *(uint4*)u;
  } else if (id < 10240) {
    const size_t i = ((size_t)(id - 4096) * 256 + t) * 8;
    float4 a = *(const float4*)(qkv_w + i), b = *(const float4*)(qkv_w + i + 4);
    unsigned short u[8] __attribute__((aligned(16)));
    u[0] = f2bu(a.x); u[1] = f2bu(a.y); u[2] = f2bu(a.z); u[3] = f2bu(a.w);
    u[4] = f2bu(b.x); u[5] = f2bu(b.y); u[6] = f2bu(b.z); u[7] = f2bu(b.w);
    *(uint4*)(qkvwb + i) = *(uint4*)u;
  } else if (id < 16384) {
    const int sub = id - 10240;
    const int w = sub >> 11, blk = sub & 2047;
    const size_t i = ((size_t)blk * 256 + t) * 4;
    const int f = (int)((i >> 18) & 3);
    const size_t off = i & 262143;
    const float* src = (w == 0) ? w0 : (w == 1) ? w1 : w2;
    float* dst = (w == 0) ? w0s : (w == 1) ? w1s : w2s;
    *(float4*)(dst + i) = *(const float4*)(src + (size_t)f * 262144 + off);
  } else if (id < 16896) {
    const int gid = (id - 16384) * 256 + t;
    const int si = gid >> 6, jj = gid & 63;
    float inv = powf(500000.0f, -(float)jj / 64.0f);
    float ang = (float)si * inv;
    ct[(size_t)si * 64 + jj] = cosf(ang);
    stb[(size_t)si * 64 + jj] = sinf(ang);
  } else {
    const int token = id - 16896, b_ = token >> 11, si = token & 2047;
    const int wv = t >> 6, lane = t & 63;
    const float* xr = x + (size_t)token * cH;
    for (int i = t; i < cH; i += 256) xbuf[i] = xr[i];
    __syncthreads();
#pragma unroll
    for (int jj = 0; jj < 3; ++jj) {
      const int j = wv * 3 + jj;
      const float* wr = lr_w + (size_t)j * cH;
      float s = 0.f;
      for (int k = lane; k < cH; k += 64) s += xbuf[k] * wr[k];
      for (int d = 32; d; d >>= 1) s += __shfl_down(s, d);
      if (lane == 0) {
        float v = s + lr_b[j] + base;
        float sp = (v > 15.f) ? v : log1pf(expf(v));
        const int tt = j >> 2, f = j & 3;
        float* dst = (tt == 0 ? lr0 : tt == 1 ? lr1 : lr2);
        dst[(size_t)(b_ * cNFW + f) * cS + si] = sp;
      }
    }
  }
}

// --- k_post2: ids 0..4095 rmsnorm+rope (qkvh writeback); 4096..5119 vtr -----
__global__ __launch_bounds__(256) void k_post2(bf16* __restrict__ qkvh,
                                               const float* __restrict__ qnw, const float* __restrict__ knw,
                                               const float* __restrict__ ct, const float* __restrict__ stb,
                                               bf16* __restrict__ qa, bf16* __restrict__ ka,
                                               bf16* __restrict__ vt) {
  __shared__ short smem[8704];
  __shared__ float red[4];
  const int id = blockIdx.x, t = threadIdx.x;
  if (id < 4096) {
    float* buf = (float*)smem;
    const int token = id, b_ = token >> 11, si = token & 2047;
    bf16* base = qkvh + (size_t)token * 3 * cH;
    for (int pass = 0; pass < 2; ++pass) {
      __syncthreads();
      bf16* src = base + pass * cH;
      const float* nw = pass ? knw : qnw;
      float ss = 0.f;
      for (int i = t; i < cH; i += 256) {
        float v = b2f(src[i]);
        buf[i] = v;
        ss += v * v;
      }
      for (int d = 32; d; d >>= 1) ss += __shfl_down(ss, d);
      if ((t & 63) == 0) red[t >> 6] = ss;
      __syncthreads();
      const float rstd = rsqrtf((red[0] + red[1] + red[2] + red[3]) / cH + 1e-6f);
      for (int i = t; i < cH; i += 256) {
        float v = buf[i] * rstd * nw[i];
        buf[i] = v;
        src[i] = f2b(v);
      }
      __syncthreads();
      bf16* dst = pass ? ka : qa;
      const float scale = pass ? 1.f : cRSQRT_HD;
      const int hh = t >> 4, j0 = (t & 15) * 4;
      const float* cr = ct + (size_t)si * 64 + j0;
      const float* sr = stb + (size_t)si * 64 + j0;
      bf16* drow = dst + ((size_t)(b_ * cNH + hh) * cS + si) * cHD;
      unsigned short u1[4] __attribute__((aligned(8))), u2[4] __attribute__((aligned(8)));
#pragma unroll
      for (int i = 0; i < 4; ++i) {
        float x1 = buf[hh * cHD + j0 + i], x2 = buf[hh * cHD + 64 + j0 + i];
        u1[i] = f2bu((x1 * cr[i] - x2 * sr[i]) * scale);
        u2[i] = f2bu((x2 * cr[i] + x1 * sr[i]) * scale);
      }
      *(uint2*)(drow + j0) = *(uint2*)u1;
      *(uint2*)(drow + 64 + j0) = *(uint2*)u2;
    }
  } else {
    short* Ts = smem;  // 64*136
    const int id2 = id - 4096;
    const int tile = id2 & 31, h = (id2 >> 5) & 15, b_ = id2 >> 9;
    {
      const int r = t >> 2, seg = (t & 3) * 32;
      const bf16* src = qkvh + ((size_t)(b_ * cS) + tile * 64 + r) * 3 * cH + 2 * cH + h * cHD + seg;
      stage16(src, &Ts[r * 136 + seg]);
      stage16(src + 16, &Ts[r * 136 + seg + 16]);
    }
    __syncthreads();
    {
      const int d = t >> 1, seg2 = (t & 1) * 32;
      unsigned short u[32] __attribute__((aligned(16)));
#pragma unroll
      for (int i = 0; i < 32; ++i) u[i] = (unsigned short)Ts[(seg2 + i) * 136 + d];
      bf16* dp = vt + ((size_t)(b_ * cNH + h) * cHD + d) * cS + tile * 64 + seg2;
      *(uint4*)dp = *(uint4*)u;
      *(uint4*)(dp + 8) = *(uint4*)(u + 8);
      *(uint4*)(dp + 16) = *(uint4*)(u + 16);
      *(uint4*)(dp + 24) = *(uint4*)(u + 24);
    }
  }
}

// --- k_mid: ids 0..4095 fq/fk/fv from qkvh; 4096..7167 mirror cvt;
//            7168..7679 w1t init (transpose of fp32 master w1s) ---
__global__ __launch_bounds__(256) void k_mid(const bf16* __restrict__ qkvh,
                                             const float* __restrict__ qk_scale,
                                             const float* __restrict__ qk_offset,
                                             bf16* fq, bf16* fk, bf16* fv,
                                             const float* __restrict__ w0s_, bf16* __restrict__ w0b_,
                                             const float* __restrict__ w1s_, bf16* __restrict__ w1t_) {
  __shared__ short Ts[64 * 72];
  const int id = blockIdx.x, t = threadIdx.x;
  if (id < 4096) {
    const int token = id, b_ = token >> 11, si = token & 2047;
    const bf16* base = qkvh + (size_t)token * 3 * cH;
#pragma unroll
    for (int pass = 0; pass < 2; ++pass) {
      const bf16* src = base + pass * cH;
      bf16* fdst = pass ? fk : fq;
      const int head = t >> 6, lane = t & 63;
      float f[8];
      float ss2 = 0.f;
#pragma unroll
      for (int k = 0; k < 8; ++k) {
        const int idx = head * cFD + lane + k * 64;
        float v = b2f(src[idx]);
        float u = v * qk_scale[idx * 2 + pass] + qk_offset[idx * 2 + pass];
        float fv_ = u * sigmoidf_(u);
        f[k] = fv_;
        ss2 += fv_ * fv_;
      }
      for (int d = 1; d < 64; d <<= 1) ss2 += __shfl_xor(ss2, d);
      const float sc2 = rsqrtf(ss2 + 1e-12f);
      bf16* dst = fdst + ((size_t)(b_ * cNFW + head) * cS + si) * cFD;
#pragma unroll
      for (int k = 0; k < 8; ++k) dst[lane + k * 64] = f2b(f[k] * sc2);
    }
    const bf16* vr = base + 2 * cH;
    for (int i = t; i < cH; i += 256) {
      float v = b2f(vr[i]);
      fv[((size_t)(b_ * cNFW + (i >> 9)) * cS + si) * cFD + (i & 511)] = f2b(v * sigmoidf_(v));
    }
  } else if (id < 7168) {
    const size_t i = ((size_t)(id - 4096) * 256 + t) * 8;
    float4 a = *(const float4*)(w0s_ + i), b = *(const float4*)(w0s_ + i + 4);
    unsigned short u[8] __attribute__((aligned(16)));
    u[0] = f2bu(a.x); u[1] = f2bu(a.y); u[2] = f2bu(a.z); u[3] = f2bu(a.w);
    u[4] = f2bu(b.x); u[5] = f2bu(b.y); u[6] = f2bu(b.z); u[7] = f2bu(b.w);
    *(uint4*)(w0b_ + i) = *(uint4*)u;
  } else {
    const int id3 = id - 7168;
    const int bh = id3 >> 6, tile = id3 & 63, by = tile >> 3, bx = tile & 7;
    {
      const int rr = t >> 2, cseg = (t & 3) * 16;
      const float* p = w1s_ + (size_t)bh * ZL_ + (size_t)(by * 64 + rr) * cFD + bx * 64 + cseg;
      unsigned short u[16] __attribute__((aligned(16)));
#pragma unroll
      for (int i = 0; i < 16; ++i) u[i] = f2bu(p[i]);
      *(uint4*)&Ts[rr * 72 + cseg] = *(uint4*)u;
      *(uint4*)&Ts[rr * 72 + cseg + 8] = *(uint4*)(u + 8);
    }
    __syncthreads();
    {
      const int oc_ = t >> 2, rseg = (t & 3) * 16;
      unsigned short u[16] __attribute__((aligned(16)));
#pragma unroll
      for (int i = 0; i < 16; ++i) u[i] = (unsigned short)Ts[(rseg + i) * 72 + oc_];
      bf16* dp = w1t_ + (size_t)bh * ZL_ + (size_t)(bx * 64 + oc_) * cFD + by * 64 + rseg;
      *(uint4*)dp = *(uint4*)u;
      *(uint4*)(dp + 8) = *(uint4*)(u + 8);
    }
  }
}

// -- attention: 128-row q blocks, 8 waves, paired tiles, XCD swizzle ---------
__global__ __launch_bounds__(512) void k_attn6(const bf16* __restrict__ qa, const bf16* __restrict__ ka,
                                               const bf16* __restrict__ vt, bf16* __restrict__ y) {
  const int id = blockIdx.x;
  const int xcd = id & 7;
  const int j = id >> 3;
  const int p = j & 7;
  const int hb = (j >> 3) * 8 + xcd;
  const int h = hb & 15, b_ = hb >> 4;
  __shared__ short KsP[9216];
  __shared__ short Vts[128 * 72];
  const int t = threadIdx.x, lane = t & 63, g = lane >> 4, c16 = lane & 15, wv = t >> 6;
  const size_t hbq = (size_t)(b_ * cNH + h) * cS;
  const bf16* vb = vt + (size_t)(b_ * cNH + h) * (size_t)(cHD * cS);
  const int r = t >> 3, seg = (t & 7) * 16;
  const int dv = t >> 2, seg2 = (t & 3) * 16;
  const f32x4 zero4 = {0.f, 0.f, 0.f, 0.f};

  for (int half = 0; half < 2; ++half) {
    const int qt = half ? p : 15 - p;
    const int q0 = qt * 128;
    const int nkt = 2 * qt + 2;
    short8 qf[4];
    {
      const bf16* qsrc = qa + (hbq + q0 + wv * 16 + c16) * cHD;
#pragma unroll
      for (int ks = 0; ks < 4; ++ks) qf[ks] = *(const short8*)(qsrc + ks * 32 + g * 8);
    }
    f32x4 o[8];
#pragma unroll
    for (int i = 0; i < 8; ++i) o[i] = zero4;
    float m[4], l[4];
#pragma unroll
    for (int rr = 0; rr < 4; ++rr) { m[rr] = -1e30f; l[rr] = 0.f; }

    uint4 kp0, kp1, vp0, vp1;
    {
      const bf16* ksrc = ka + (hbq + r) * cHD + seg;
      kp0 = *(const uint4*)ksrc; kp1 = *(const uint4*)(ksrc + 8);
      const bf16* vsrc = vb + (size_t)dv * cS + seg2;
      vp0 = *(const uint4*)vsrc; vp1 = *(const uint4*)(vsrc + 8);
    }

    for (int kt = 0; kt < nkt; ++kt) {
      __syncthreads();
      {
        short* kd = &KsP[r * 136 + seg];
        *(uint4*)kd = kp0; *(uint4*)(kd + 8) = kp1;
        short* vd = &Vts[dv * 72 + seg2];
        *(uint4*)vd = vp0; *(uint4*)(vd + 8) = vp1;
      }
      __syncthreads();
      if (kt + 1 < nkt) {
        const bf16* ksrc = ka + (hbq + (kt + 1) * 64 + r) * cHD + seg;
        kp0 = *(const uint4*)ksrc; kp1 = *(const uint4*)(ksrc + 8);
        const bf16* vsrc = vb + (size_t)dv * cS + (kt + 1) * 64 + seg2;
        vp0 = *(const uint4*)vsrc; vp1 = *(const uint4*)(vsrc + 8);
      } else if (half == 0) {
        const bf16* ksrc = ka + (hbq + r) * cHD + seg;
        kp0 = *(const uint4*)ksrc; kp1 = *(const uint4*)(ksrc + 8);
        const bf16* vsrc = vb + (size_t)dv * cS + seg2;
        vp0 = *(const uint4*)vsrc; vp1 = *(const uint4*)(vsrc + 8);
      }

      f32x4 s4[4];
#pragma unroll
      for (int ni = 0; ni < 4; ++ni) s4[ni] = zero4;
      __builtin_amdgcn_s_setprio(1);
#pragma unroll
      for (int ks = 0; ks < 4; ++ks) {
#pragma unroll
        for (int ni = 0; ni < 4; ++ni) {
          short8 bb = *(const short8*)&KsP[(ni * 16 + c16) * 136 + ks * 32 + g * 8];
          s4[ni] = __builtin_amdgcn_mfma_f32_16x16x32_bf16(qf[ks], bb, s4[ni], 0, 0, 0);
        }
      }
      __builtin_amdgcn_s_setprio(0);
      __syncthreads();
      if (kt * 64 + 64 > q0) {
#pragma unroll
        for (int ni = 0; ni < 4; ++ni) {
          const int kv = kt * 64 + ni * 16 + c16;
#pragma unroll
          for (int rr = 0; rr < 4; ++rr) {
            const int qr = q0 + wv * 16 + g * 4 + rr;
            if (kv > qr) s4[ni][rr] = -1e9f;
          }
        }
      }
      float mx[4];
#pragma unroll
      for (int rr = 0; rr < 4; ++rr)
        mx[rr] = fmaxf(fmaxf(s4[0][rr], s4[1][rr]), fmaxf(s4[2][rr], s4[3][rr]));
#pragma unroll
      for (int d = 1; d < 16; d <<= 1)
#pragma unroll
        for (int rr = 0; rr < 4; ++rr) mx[rr] = fmaxf(mx[rr], __shfl_xor(mx[rr], d));
      bool need = false;
#pragma unroll
      for (int rr = 0; rr < 4; ++rr) need |= (mx[rr] > m[rr] + 8.f);
      if (__any(need)) {
        float corr[4];
#pragma unroll
        for (int rr = 0; rr < 4; ++rr) {
          float mn = fmaxf(m[rr], mx[rr]);
          corr[rr] = __expf(m[rr] - mn);
          m[rr] = mn;
        }
#pragma unroll
        for (int rr = 0; rr < 4; ++rr) l[rr] *= corr[rr];
#pragma unroll
        for (int nf = 0; nf < 8; ++nf)
#pragma unroll
          for (int rr = 0; rr < 4; ++rr) o[nf][rr] *= corr[rr];
      }
      float psum[4] = {0.f, 0.f, 0.f, 0.f};
#pragma unroll
      for (int ni = 0; ni < 4; ++ni)
#pragma unroll
        for (int rr = 0; rr < 4; ++rr) {
          float pp = __expf(s4[ni][rr] - m[rr]);
          s4[ni][rr] = pp;
          psum[rr] += pp;
        }
#pragma unroll
      for (int d = 1; d < 16; d <<= 1)
#pragma unroll
        for (int rr = 0; rr < 4; ++rr) psum[rr] += __shfl_xor(psum[rr], d);
#pragma unroll
      for (int rr = 0; rr < 4; ++rr) l[rr] += psum[rr];
      short* pw = &KsP[wv * 1152];
#pragma unroll
      for (int ni = 0; ni < 4; ++ni)
#pragma unroll
        for (int rr = 0; rr < 4; ++rr)
          pw[(g * 4 + rr) * 72 + ni * 16 + c16] = (short)f2bu(s4[ni][rr]);
      __builtin_amdgcn_s_setprio(1);
#pragma unroll
      for (int ks2 = 0; ks2 < 2; ++ks2) {
        short8 a = *(const short8*)&pw[c16 * 72 + ks2 * 32 + g * 8];
#pragma unroll
        for (int nf = 0; nf < 8; ++nf) {
          short8 bb = *(const short8*)&Vts[(nf * 16 + c16) * 72 + ks2 * 32 + g * 8];
          o[nf] = __builtin_amdgcn_mfma_f32_16x16x32_bf16(a, bb, o[nf], 0, 0, 0);
        }
      }
      __builtin_amdgcn_s_setprio(0);
    }
    float inv[4];
#pragma unroll
    for (int rr = 0; rr < 4; ++rr) inv[rr] = 1.f / l[rr];
#pragma unroll
    for (int nf = 0; nf < 8; ++nf)
#pragma unroll
      for (int rr = 0; rr < 4; ++rr) {
        const size_t row = (size_t)(b_ * cS) + q0 + wv * 16 + g * 4 + rr;
        y[row * cH + h * cHD + nf * 16 + c16] = f2b(o[nf][rr] * inv[rr]);
      }
  }
}

}  // namespace

extern "C" void kernel_launch(void* const* d_in, const int* in_sizes, int n_in,
                              void* d_out, int out_size, void* d_ws, size_t ws_size,
                              hipStream_t stream) {
  (void)in_sizes; (void)n_in; (void)out_size; (void)ws_size;
  const float* x         = (const float*)d_in[0];
  const float* qkv_w     = (const float*)d_in[1];
  const float* q_norm_w  = (const float*)d_in[2];
  const float* k_norm_w  = (const float*)d_in[3];
  const float* qk_scale  = (const float*)d_in[4];
  const float* qk_offset = (const float*)d_in[5];
  const float* lr_w      = (const float*)d_in[6];
  const float* lr_b      = (const float*)d_in[7];
  const float* w0        = (const float*)d_in[8];
  const float* w1        = (const float*)d_in[9];
  const float* w2        = (const float*)d_in[10];
  const float* ttt_nw    = (const float*)d_in[11];
  const float* o_proj_w  = (const float*)d_in[12];
  float* out = (float*)d_out;

  // ---- workspace layout (bytes), total 143,851,520 (proven footprint) ----
  char* Wb = (char*)d_ws;
  bf16* qkvh = (bf16*)Wb;                 // phase-1 only (50.3MB)
  bf16* hq   = (bf16*)(Wb + 0UL);         // TTT phase buffers:
  bf16* trH  = (bf16*)(Wb + 4194304UL);
  bf16* trD1 = (bf16*)(Wb + 8388608UL);
  bf16* trD2 = (bf16*)(Wb + 12582912UL);
  bf16* trK  = (bf16*)(Wb + 16777216UL);
  bf16* trV  = (bf16*)(Wb + 20971520UL);
  bf16* occ  = (bf16*)(Wb + 25165824UL);
  bf16* w1t  = (bf16*)(Wb + 29360128UL);  // transposed w1 mirror
  bf16* w0b  = (bf16*)(Wb + 33554432UL);  // contiguous mirrors w0b,w1b0,w2b
  bf16* w1b0 = (bf16*)(Wb + 37748736UL);
  bf16* w2b  = (bf16*)(Wb + 41943040UL);
  bf16* w1b1 = (bf16*)(Wb + 46137344UL);  // w1 row-major mirror ping-pong
  bf16* opwb = (bf16*)(Wb + 0UL);         // after TTT loop
  size_t off = 50331648UL;
  bf16* fqb = (bf16*)(Wb + off); off += 16777216UL;
  bf16* fkb = (bf16*)(Wb + off); off += 16777216UL;
  bf16* fvb = (bf16*)(Wb + off); off += 16777216UL;
  float* w0s = (float*)(Wb + off); off += 8388608UL;
  float* w1s = (float*)(Wb + off); off += 8388608UL;
  float* w2s = (float*)(Wb + off); off += 8388608UL;
  float* lr0 = (float*)(Wb + off); off += 65536UL;
  float* lr1 = (float*)(Wb + off); off += 65536UL;
  float* lr2 = (float*)(Wb + off); off += 65536UL;
  bf16* y = (bf16*)(Wb + off); off += 16777216UL;
  float* ct  = (float*)(Wb + off); off += 524288UL;
  float* stb = (float*)(Wb + off); off += 524288UL;
  bf16* xb = fqb;
  bf16* qkvwb = fkb;
  bf16* qa = fqb;
  bf16* ka = fkb;
  bf16* vt = fvb;
  bf16* w1m[2] = {w1b0, w1b1};

  const float base_lr_inv = logf(expm1f(0.001f));
  dim3 blk(256);

  k_prep<<<dim3(20992), blk, 0, stream>>>(x, qkv_w, w0, w1, w2, lr_w, lr_b,
                                          xb, qkvwb, w0s, w1s, w2s, ct, stb,
                                          lr0, lr1, lr2, base_lr_inv);
  k_mm8<bf16><<<dim3(48, 16), dim3(512), 0, stream>>>(xb, 2048, qkvwb, 2048, qkvh, 6144, 2048);
  k_post2<<<dim3(5120), blk, 0, stream>>>(qkvh, q_norm_w, k_norm_w, ct, stb, qa, ka, vt);
  k_attn6<<<dim3(256), dim3(512), 0, stream>>>(qa, ka, vt, y);
  // fq/fk/fv overwrite qa/ka/vt after attn; mirrors + w1t init in same launch
  k_mid<<<dim3(7680), blk, 0, stream>>>(qkvh, qk_scale, qk_offset, fqb, fkb, fvb,
                                        w0s, w0b, w1s, w1t);

  for (int c = 0; c < 4; ++c) {
    const int g1 = (c == 0) ? 1536 : 5632;
    k_fuse1<<<dim3(g1), blk, 0, stream>>>(fqb, fkb, fvb, w0b, w1t, w2b,
                                          hq, trH, trD1, trD2, trK, trV,
                                          lr0, lr1, lr2, occ, ttt_nw, y, c);
    k_updna<<<dim3(512), blk, 0, stream>>>(trV, trH, trD1, trD2, trK, hq, w1m[c & 1],
                                           w0s, w1s, w2s, w0b, w1m[(c + 1) & 1], w2b, w1t,
                                           occ);
  }
  k_normcvt<<<dim3(6144), blk, 0, stream>>>(occ, ttt_nw, y, o_proj_w, opwb, 3);
  k_mm8<float><<<dim3(16, 16), dim3(512), 0, stream>>>(y, 2048, opwb, 2048, out, 2048, 2048);
}